// Round 11
// baseline (269.381 us; speedup 1.0000x reference)
//
#include <hip/hip_runtime.h>
#include <math.h>

#define G 64
#define GV (G*G*G)      // 262144
#define NB 8

typedef unsigned short u16;
typedef unsigned int u32;
typedef unsigned long long U64;
typedef __bf16 bf16x8 __attribute__((ext_vector_type(8)));
typedef float f32x4 __attribute__((ext_vector_type(4)));

union BF8 { u16 s[8]; bf16x8 v; };

__device__ __forceinline__ float bf2f(u16 h) {
    union { u32 u; float f; } c; c.u = ((u32)h) << 16; return c.f;
}
__device__ __forceinline__ u16 f2bf(float f) {
    union { float f; u32 u; } c; c.f = f;
    u32 u = c.u;
    return (u16)((u + 0x7fffu + ((u >> 16) & 1u)) >> 16);   // RNE
}
__device__ __forceinline__ u32 cvt_pk_bf16(float lo, float hi) {
    u32 r;
    asm volatile("v_cvt_pk_bf16_f32 %0, %1, %2" : "=v"(r) : "v"(lo), "v"(hi));
    return r;
}

#define YSTRIDE 36   // u32 per voxel row; b128-aligned, 2-way banks
#define POOLB 24576  // shared pool bytes (union of convA / topk1 needs)

// ---------------------------------------------------------------------------
// convA body (R10-proven): bf16 weights, 8 MFMA / 16-voxel tile,
// per-wave LDS Y exchange, 1-deep pipeline.
// pool layout: halo u16[2378] @0 (4756B, pad to 4768) | shpool u32[4608]
// ---------------------------------------------------------------------------
__device__ void convA_body(
    int box, int b, char* pool,
    const float* __restrict__ bnd,
    const float* __restrict__ w1, const float* __restrict__ b1,
    const float* __restrict__ w2,
    u16* __restrict__ zbuf)
{
    const float* bd = bnd + (size_t)b * GV;
    u16* zb = zbuf + (size_t)b * (27 * (size_t)GV);

    u16* halo   = (u16*)pool;            // 2378 u16
    u32* shpool = (u32*)(pool + 4768);   // 4608 u32

    int tid = threadIdx.x;
    int z0 = (box >> 4) * 4, y0 = (box & 15) * 4;

    // coalesced weight stage
    {
        float* ldsW = (float*)shpool;
        for (int i = tid; i < 3520; i += 256) {
            float v;
            if (i < 1728)      v = w1[i];
            else if (i < 3456) v = w2[i - 1728];
            else               v = b1[i - 3456];
            ldsW[i] = v;
        }
    }

    // halo fill (bf16 bit patterns)
    for (int i = tid; i < 2378; i += 256) {
        u16 hval = 0;
        if (i < 2376) {
            int hz = i / 396, rem = i - hz * 396;
            int hy = rem / 66, hx = rem - hy * 66;
            int gz = z0 + hz - 1, gy = y0 + hy - 1, gx = hx - 1;
            if (((unsigned)gz < (unsigned)G) & ((unsigned)gy < (unsigned)G) &
                ((unsigned)gx < (unsigned)G)) {
                float f = bd[(gz << 12) + (gy << 6) + gx];
                hval = (f > 0.5f) ? (u16)0x3F80 : (u16)0;
            }
        }
        halo[i] = hval;
    }

    __syncthreads();

    int wv = tid >> 6, lane = tid & 63;
    int g = lane >> 4, lr = lane & 15;

    const float* ldsW = (const float*)shpool;
    BF8 w1A[4];
#pragma unroll
    for (int m = 0; m < 4; m++) {
        int c = 16 * m + lr;
#pragma unroll
        for (int j = 0; j < 8; j++) {
            int kk = 8 * g + j;
            float w = (kk < 27) ? ldsW[c * 27 + kk] : 0.0f;
            w1A[m].s[j] = f2bf(w);
        }
    }
    BF8 w2A[2][2];
#pragma unroll
    for (int m2 = 0; m2 < 2; m2++) {
        int t = 16 * m2 + lr;
#pragma unroll
        for (int ks = 0; ks < 2; ks++)
#pragma unroll
            for (int j = 0; j < 8; j++) {
                int ch = 32 * ks + 8 * g + j;
                float w = (t < 27) ? ldsW[1728 + ch * 27 + t] : 0.0f;
                w2A[m2][ks].s[j] = f2bf(w);
            }
    }
    float bias[4][4];
#pragma unroll
    for (int m = 0; m < 4; m++)
#pragma unroll
        for (int r = 0; r < 4; r++) bias[m][r] = ldsW[3456 + 16 * m + 4 * g + r];

    int tapoff[8];
#pragma unroll
    for (int j = 0; j < 8; j++) {
        int kk = 8 * g + j;
        int kc = kk < 27 ? kk : 0;
        int dz = kc / 9, ry = kc - dz * 9;
        int dy = ry / 3, dx = ry - dy * 3;
        tapoff[j] = dz * 396 + dy * 66 + dx;
    }

    __syncthreads();    // weights region dead -> Y buffers

    u32* myY0 = shpool + wv * (2 * 16 * YSTRIDE);
    u32* myY1 = myY0 + 16 * YSTRIDE;

    auto gemm1pack = [&](int IT, u32* DST) {
        int li = IT >> 2, xt = IT & 3;
        int l = wv * 4 + li;
        int lineoff = ((l >> 2) * 6 + (l & 3)) * 66 + lr + xt * 16;

        BF8 xB;
#pragma unroll
        for (int j = 0; j < 8; j++)
            xB.s[j] = halo[lineoff + tapoff[j]];

        f32x4 yac[4];
#pragma unroll
        for (int m = 0; m < 4; m++) {
            f32x4 c0;
            c0[0] = bias[m][0]; c0[1] = bias[m][1];
            c0[2] = bias[m][2]; c0[3] = bias[m][3];
            yac[m] = __builtin_amdgcn_mfma_f32_16x16x32_bf16(
                w1A[m].v, xB.v, c0, 0, 0, 0);
        }

#pragma unroll
        for (int m = 0; m < 4; m++) {
            float a0 = fmaxf(yac[m][0], 0.f), a1 = fmaxf(yac[m][1], 0.f);
            float a2 = fmaxf(yac[m][2], 0.f), a3 = fmaxf(yac[m][3], 0.f);
            u32 h01 = cvt_pk_bf16(a0, a1);
            u32 h23 = cvt_pk_bf16(a2, a3);
            *(U64*)&DST[lr * YSTRIDE + 8 * m + 2 * g] =
                (U64)h01 | ((U64)h23 << 32);
        }
    };

    auto gemm2store = [&](int IT, const u32* SRC) {
        int li = IT >> 2, xt = IT & 3;
        int l = wv * 4 + li;
        int vbase = ((z0 + (l >> 2)) << 12) + ((y0 + (l & 3)) << 6) + xt * 16;

        f32x4 zac[2];
        zac[0] = f32x4{0.f, 0.f, 0.f, 0.f};
        zac[1] = f32x4{0.f, 0.f, 0.f, 0.f};
#pragma unroll
        for (int ks = 0; ks < 2; ks++) {
            bf16x8 yBh = *(const bf16x8*)&SRC[lr * YSTRIDE + 16 * ks + 4 * g];
#pragma unroll
            for (int m2 = 0; m2 < 2; m2++)
                zac[m2] = __builtin_amdgcn_mfma_f32_16x16x32_bf16(
                    w2A[m2][ks].v, yBh, zac[m2], 0, 0, 0);
        }

        int vg = vbase + lr;
#pragma unroll
        for (int m2 = 0; m2 < 2; m2++)
#pragma unroll
            for (int r = 0; r < 4; r++) {
                int t = 16 * m2 + 4 * g + r;
                if (t < 27)
                    zb[(size_t)t * GV + vg] = f2bf(zac[m2][r]);
            }
    };

    gemm1pack(0, myY0);
    for (int it = 1; it < 16; ++it) {
        u32* cur  = (it & 1) ? myY1 : myY0;
        u32* prev = (it & 1) ? myY0 : myY1;
        gemm1pack(it, cur);
        asm volatile("" ::: "memory");
        gemm2store(it - 1, prev);
    }
    asm volatile("" ::: "memory");
    gemm2store(15, myY1);
}

// ---------------------------------------------------------------------------
// convB body: x2(v) = relu(b2 + sum_t z_t(v + d_t))
// ---------------------------------------------------------------------------
__device__ void convB_body(
    int vblk, int b,
    const u16* __restrict__ zbuf, float* __restrict__ xout,
    const float* __restrict__ b2)
{
    const u16* zb = zbuf + (size_t)b * (27 * (size_t)GV);
    float* xo = xout + (size_t)b * GV;

    int v  = vblk * 256 + threadIdx.x;
    int zc = v >> 12, yc = (v >> 6) & 63, xc = v & 63;
    float acc = b2[0];
#pragma unroll
    for (int dz = -1; dz <= 1; dz++)
#pragma unroll
    for (int dy = -1; dy <= 1; dy++)
#pragma unroll
    for (int dx = -1; dx <= 1; dx++) {
        int t = (dz + 1) * 9 + (dy + 1) * 3 + (dx + 1);
        int zz = zc + dz, yy = yc + dy, xx = xc + dx;
        bool ok = ((unsigned)zz < (unsigned)G) & ((unsigned)yy < (unsigned)G) &
                  ((unsigned)xx < (unsigned)G);
        if (ok) acc += bf2f(zb[(size_t)t * GV + (zz << 12) + (yy << 6) + xx]);
    }
    xo[v] = fmaxf(acc, 0.0f);
}

// ---------------------------------------------------------------------------
#define BPB 32
#define IDXM 0x3FFFFu

// topk1 body (also zeros its slice of points output)
// pool: lcand U64[2560] @0 | rv U64[256] @20480 | rp int[256] @22528
__device__ void topk1_body(
    int blk, int b, char* pool,
    const float* __restrict__ bnd, const float* __restrict__ noise,
    U64* __restrict__ cand, float4* __restrict__ pts_out)
{
    int tid = threadIdx.x;
    int vbase = blk * (GV / BPB);

    float4* zp = pts_out + ((size_t)b * GV + vbase) / 4;
#pragma unroll
    for (int i = 0; i < 8; i++)
        zp[i * 256 + tid] = make_float4(0.f, 0.f, 0.f, 0.f);

    const float* bd = bnd + (size_t)b * GV + vbase;
    const float* nz = noise + (size_t)b * GV + vbase;

    U64 top[10];
#pragma unroll
    for (int k = 0; k < 10; k++) top[k] = 0ull;

    for (int i = 0; i < (GV / BPB) / 256; i++) {
        int e = i * 256 + tid;
        float bv = bd[e];
        float s  = nz[e];
        U64 p = (bv > 0.5f) ? 0ull
              : ((((U64)__float_as_uint(s)) << 32) |
                 (IDXM - (unsigned)(vbase + e)));
        if (p > top[9]) {
#pragma unroll
            for (int k = 0; k < 10; k++) {
                U64 mx = p > top[k] ? p : top[k];
                U64 mn = p > top[k] ? top[k] : p;
                top[k] = mx; p = mn;
            }
        }
    }

    U64* lcand = (U64*)pool;             // 2560
    U64* rv    = (U64*)(pool + 20480);   // 256
    int* rp    = (int*)(pool + 22528);   // 256
#pragma unroll
    for (int k = 0; k < 10; k++) lcand[tid * 10 + k] = top[k];
    __syncthreads();

    for (int pass = 0; pass < 10; pass++) {
        U64 bv = 0; int bp = 0;
        for (int i = tid; i < 2560; i += 256) {
            U64 xv = lcand[i];
            if (xv > bv) { bv = xv; bp = i; }
        }
        rv[tid] = bv; rp[tid] = bp;
        __syncthreads();
        for (int off = 128; off > 0; off >>= 1) {
            if (tid < off) {
                if (rv[tid + off] > rv[tid]) { rv[tid] = rv[tid + off]; rp[tid] = rp[tid + off]; }
            }
            __syncthreads();
        }
        if (tid == 0) {
            cand[((size_t)b * BPB + blk) * 10 + pass] = rv[0];
            lcand[rp[0]] = 0ull;
        }
        __syncthreads();
    }
}

// ---------------------------------------------------------------------------
// K1: convA batches 0-3
__global__ __launch_bounds__(256) void k1_kernel(
    const float* __restrict__ bnd, const float* __restrict__ w1,
    const float* __restrict__ b1, const float* __restrict__ w2,
    u16* __restrict__ zbuf)
{
    __shared__ __align__(16) char pool[POOLB];
    int bid = blockIdx.x;
    convA_body(bid & 255, bid >> 8, pool, bnd, w1, b1, w2, zbuf);
}

// K2: convA batches 4-7 (blocks 0..1023) + convB batches 0-3 (blocks 1024..5119)
__global__ __launch_bounds__(256) void k2_kernel(
    const float* __restrict__ bnd, const float* __restrict__ w1,
    const float* __restrict__ b1, const float* __restrict__ w2,
    u16* __restrict__ zbuf, float* __restrict__ xout,
    const float* __restrict__ b2)
{
    __shared__ __align__(16) char pool[POOLB];
    int bid = blockIdx.x;
    if (bid < 1024) {
        convA_body(bid & 255, 4 + (bid >> 8), pool, bnd, w1, b1, w2, zbuf);
    } else {
        int r = bid - 1024;
        convB_body(r & 1023, r >> 10, zbuf, xout, b2);
    }
}

// K3: topk1 all batches (blocks 0..255) + convB batches 4-7 (blocks 256..4351)
__global__ __launch_bounds__(256) void k3_kernel(
    const float* __restrict__ bnd, const float* __restrict__ noise,
    U64* __restrict__ cand, float4* __restrict__ pts_out,
    const u16* __restrict__ zbuf, float* __restrict__ xout,
    const float* __restrict__ b2)
{
    __shared__ __align__(16) char pool[POOLB];
    int bid = blockIdx.x;
    if (bid < 256) {
        topk1_body(bid & 31, bid >> 5, pool, bnd, noise, cand, pts_out);
    } else {
        int r = bid - 256;
        convB_body(r & 1023, 4 + (r >> 10), zbuf, xout, b2);
    }
}

// ---------------------------------------------------------------------------
// fc1: unchanged (R10)
// ---------------------------------------------------------------------------
__global__ __launch_bounds__(256) void fc1_kernel(
    const float* __restrict__ W, const float* __restrict__ x,
    float* __restrict__ pacc)
{
    int jt = blockIdx.x;            // 0..31
    int vc = blockIdx.y;            // 0..63
    int tid = threadIdx.x;
    int j0 = jt * 8;
    size_t v0 = (size_t)vc * 4096;

    const f32x4* Wp[8];
#pragma unroll
    for (int jj = 0; jj < 8; jj++)
        Wp[jj] = reinterpret_cast<const f32x4*>(W + (size_t)(j0 + jj) * GV + v0);
    const f32x4* Xp[NB];
#pragma unroll
    for (int b = 0; b < NB; b++)
        Xp[b] = reinterpret_cast<const f32x4*>(x + (size_t)b * GV + v0);

    float acc[8][NB];
#pragma unroll
    for (int jj = 0; jj < 8; jj++)
#pragma unroll
        for (int b = 0; b < NB; b++) acc[jj][b] = 0.0f;

    for (int i = 0; i < 4; i++) {
        int e = i * 256 + tid;
        f32x4 wvv[8];
#pragma unroll
        for (int jj = 0; jj < 8; jj++)
            wvv[jj] = __builtin_nontemporal_load(&Wp[jj][e]);
        f32x4 xv[NB];
#pragma unroll
        for (int b = 0; b < NB; b++) xv[b] = Xp[b][e];
#pragma unroll
        for (int b = 0; b < NB; b++) {
#pragma unroll
            for (int jj = 0; jj < 8; jj++) {
                acc[jj][b] = fmaf(wvv[jj][0], xv[b][0], acc[jj][b]);
                acc[jj][b] = fmaf(wvv[jj][1], xv[b][1], acc[jj][b]);
                acc[jj][b] = fmaf(wvv[jj][2], xv[b][2], acc[jj][b]);
                acc[jj][b] = fmaf(wvv[jj][3], xv[b][3], acc[jj][b]);
            }
        }
    }

    __shared__ float sacc[256][36];
    __shared__ float p2[8][40];
#pragma unroll
    for (int pass = 0; pass < 2; pass++) {
        if (pass > 0) __syncthreads();
        float4* row = reinterpret_cast<float4*>(&sacc[tid][0]);
#pragma unroll
        for (int jj = 0; jj < 4; jj++) {
            int js = pass * 4 + jj;
            row[jj * 2 + 0] = make_float4(acc[js][0], acc[js][1], acc[js][2], acc[js][3]);
            row[jj * 2 + 1] = make_float4(acc[js][4], acc[js][5], acc[js][6], acc[js][7]);
        }
        __syncthreads();
        {
            int o = tid & 31, gg = tid >> 5;
            float s = 0.0f;
#pragma unroll
            for (int k = 0; k < 32; k++) s += sacc[gg * 32 + k][o];
            p2[gg][o] = s;
        }
        __syncthreads();
        if (tid < 32) {
            float s = 0.0f;
#pragma unroll
            for (int gg = 0; gg < 8; gg++) s += p2[gg][tid];
            int jj = tid >> 3, b = tid & 7;
            pacc[((size_t)b * 64 + vc) * 256 + (j0 + pass * 4 + jj)] = s;
        }
    }
}

// ---------------------------------------------------------------------------
// finalize: blocks 0..7 topk2 per batch; block 8 fc_final (unchanged R10)
// ---------------------------------------------------------------------------
__global__ __launch_bounds__(256) void finalize_kernel(
    const U64* __restrict__ cand, float* __restrict__ pts,
    const float* __restrict__ pacc, const float* __restrict__ fc1_b,
    const float* __restrict__ fc2_w, const float* __restrict__ fc2_b,
    float* __restrict__ prob)
{
    int tid = threadIdx.x;

    if (blockIdx.x < 8) {
        int b = blockIdx.x;
        __shared__ U64 lc[BPB * 10];
        __shared__ U64 rv[256];
        __shared__ int rp[256];
        __shared__ int widx[10];
        for (int i = tid; i < BPB * 10; i += 256) lc[i] = cand[(size_t)b * BPB * 10 + i];
        __syncthreads();

        for (int pass = 0; pass < 10; pass++) {
            U64 bv = 0; int bp = 0;
            for (int i = tid; i < BPB * 10; i += 256) {
                U64 xv = lc[i];
                if (xv > bv) { bv = xv; bp = i; }
            }
            rv[tid] = bv; rp[tid] = bp;
            __syncthreads();
            for (int off = 128; off > 0; off >>= 1) {
                if (tid < off) {
                    if (rv[tid + off] > rv[tid]) { rv[tid] = rv[tid + off]; rp[tid] = rp[tid + off]; }
                }
                __syncthreads();
            }
            if (tid == 0) { widx[pass] = (int)(IDXM - (u32)(rv[0] & 0xffffffffu)); lc[rp[0]] = 0ull; }
            __syncthreads();
        }
        if (tid < 10) pts[(size_t)b * GV + widx[tid]] = 1.0f;
    } else {
        int j = tid;
        float h[NB];
#pragma unroll
        for (int b = 0; b < NB; b++) h[b] = 0.0f;
        for (int c = 0; c < 64; c++) {
#pragma unroll
            for (int b = 0; b < NB; b++)
                h[b] += pacc[((size_t)b * 64 + c) * 256 + j];
        }
        float w2j = fc2_w[j];
        float contrib[NB];
#pragma unroll
        for (int b = 0; b < NB; b++)
            contrib[b] = fmaxf(h[b] + fc1_b[j], 0.0f) * w2j;

        int lane = j & 63, wid = j >> 6;
#pragma unroll
        for (int b = 0; b < NB; b++)
#pragma unroll
            for (int off = 32; off > 0; off >>= 1)
                contrib[b] += __shfl_down(contrib[b], off, 64);

        __shared__ float sred[4][NB];
        if (lane == 0) {
#pragma unroll
            for (int b = 0; b < NB; b++) sred[wid][b] = contrib[b];
        }
        __syncthreads();
        if (j < NB) {
            float t = sred[0][j] + sred[1][j] + sred[2][j] + sred[3][j] + fc2_b[0];
            prob[j] = 100.0f / (1.0f + expf(-t));
        }
    }
}

// ---------------------------------------------------------------------------
extern "C" void kernel_launch(void* const* d_in, const int* in_sizes, int n_in,
                              void* d_out, int out_size, void* d_ws, size_t ws_size,
                              hipStream_t stream)
{
    const float* bnd   = (const float*)d_in[0];
    const float* w1    = (const float*)d_in[1];
    const float* b1    = (const float*)d_in[2];
    const float* w2    = (const float*)d_in[3];
    const float* b2    = (const float*)d_in[4];
    const float* fw1   = (const float*)d_in[5];
    const float* fb1   = (const float*)d_in[6];
    const float* fw2   = (const float*)d_in[7];
    const float* fb2   = (const float*)d_in[8];
    const float* noise = (const float*)d_in[9];

    float* out = (float*)d_out;
    char* ws = (char*)d_ws;

    const size_t xbuf_off = 0;                                 // 8 MB
    const size_t pacc_off = xbuf_off + (size_t)NB * GV * 4;    // 512 KB
    const size_t cand_off = pacc_off + (size_t)NB * 64 * 256 * 4;
    const size_t zbuf_off = cand_off + (size_t)NB * BPB * 10 * 8;

    float* xbuf = (float*)(ws + xbuf_off);
    float* pacc = (float*)(ws + pacc_off);
    U64*   cand = (U64*)(ws + cand_off);
    u16*   zbuf = (u16*)(ws + zbuf_off);                       // 8 x 13.5 MB

    // K1: convA b0-3
    k1_kernel<<<1024, 256, 0, stream>>>(bnd, w1, b1, w2, zbuf);

    // K2: convA b4-7 + convB b0-3 (overlap compute with BW stream)
    k2_kernel<<<5120, 256, 0, stream>>>(bnd, w1, b1, w2, zbuf, xbuf, b2);

    // K3: topk1 (all batches, zeroes points) + convB b4-7
    k3_kernel<<<4352, 256, 0, stream>>>(bnd, noise, cand, (float4*)out,
                                        zbuf, xbuf, b2);

    dim3 gfc(32, 64);
    fc1_kernel<<<gfc, 256, 0, stream>>>(fw1, xbuf, pacc);

    finalize_kernel<<<9, 256, 0, stream>>>(cand, out, pacc, fb1, fw2, fb2,
                                           out + (size_t)NB * GV);
}

// Round 12
// 184.347 us; speedup vs baseline: 1.4613x; 1.4613x over previous
//
#include <hip/hip_runtime.h>
#include <math.h>

#define G 64
#define GV (G*G*G)      // 262144
#define NB 8
#define NP 9            // zrow planes (dz,dy)

typedef unsigned short u16;
typedef unsigned int u32;
typedef unsigned long long U64;
typedef __bf16 bf16x8 __attribute__((ext_vector_type(8)));
typedef float f32x4 __attribute__((ext_vector_type(4)));

union BF8 { u16 s[8]; bf16x8 v; };

__device__ __forceinline__ float bf2f(u16 h) {
    union { u32 u; float f; } c; c.u = ((u32)h) << 16; return c.f;
}
__device__ __forceinline__ u16 f2bf(float f) {
    union { float f; u32 u; } c; c.f = f;
    u32 u = c.u;
    return (u16)((u + 0x7fffu + ((u >> 16) & 1u)) >> 16);   // RNE
}
__device__ __forceinline__ u32 cvt_pk_bf16(float lo, float hi) {
    u32 r;
    asm volatile("v_cvt_pk_bf16_f32 %0, %1, %2" : "=v"(r) : "v"(lo), "v"(hi));
    return r;
}

#define YSTRIDE 36   // u32 per x-row; stride%32=4 banks -> free 2-way conflict

// ---------------------------------------------------------------------------
// convA via MFMA, x-taps folded (9 output planes):
//   per wave, per line (fixed z,y; x=0..63):
//     GEMM1 x4 tiles: Y^T[64c x 16v] = W1 @ X^T (+bias) -> relu -> bf16
//                     -> LDS Y-line [66 rows][36 u32], rows 0/65 = 0 (pad)
//     GEMM2 x4 tiles: zrow_p(x) = sum_dx (W2dx @ Y(.+dx-1))[p][x], p=(dz,dy)
//                     6 MFMA (3 dx * 2 K-halves), 9 rows -> global bf16
// Eliminates 2/3 of z HBM traffic (27 -> 9 planes).
// Block: 256 thr = 4 waves, box 4z x 4y x 64x; 4 lines/wave.
// ---------------------------------------------------------------------------
__global__ __launch_bounds__(256) void convA_mfma_kernel(
    const float* __restrict__ bnd,
    const float* __restrict__ w1, const float* __restrict__ b1,
    const float* __restrict__ w2,
    u16* __restrict__ zbuf)
{
    int b = blockIdx.y;
    const float* bd = bnd + (size_t)b * GV;
    u16* zb = zbuf + (size_t)b * (NP * (size_t)GV);

    __shared__ __align__(16) u16 halo[2378];          // 6*6*66 + pad
    __shared__ __align__(16) u32 Ylds[4][66 * YSTRIDE];

    int tid = threadIdx.x;
    int z0 = (blockIdx.x >> 4) * 4, y0 = (blockIdx.x & 15) * 4;

    // ---- coalesced weight stage (into Ylds region, dead until GEMM phase) ----
    {
        float* ldsW = (float*)&Ylds[0][0];
        for (int i = tid; i < 3520; i += 256) {
            float v;
            if (i < 1728)      v = w1[i];
            else if (i < 3456) v = w2[i - 1728];
            else               v = b1[i - 3456];
            ldsW[i] = v;
        }
    }

    // ---- halo fill (bf16 bit patterns 0x3F80 / 0) ----
    for (int i = tid; i < 2378; i += 256) {
        u16 hval = 0;
        if (i < 2376) {
            int hz = i / 396, rem = i - hz * 396;
            int hy = rem / 66, hx = rem - hy * 66;
            int gz = z0 + hz - 1, gy = y0 + hy - 1, gx = hx - 1;
            if (((unsigned)gz < (unsigned)G) & ((unsigned)gy < (unsigned)G) &
                ((unsigned)gx < (unsigned)G)) {
                float f = bd[(gz << 12) + (gy << 6) + gx];
                hval = (f > 0.5f) ? (u16)0x3F80 : (u16)0;
            }
        }
        halo[i] = hval;
    }

    __syncthreads();

    int wv = tid >> 6, lane = tid & 63;
    int g = lane >> 4, lr = lane & 15;

    // ---- fragment build from LDS (bf16 weights) ----
    const float* ldsW = (const float*)&Ylds[0][0];
    BF8 w1A[4];                     // GEMM1 A: 4 c-tiles, K=27 pad 32
#pragma unroll
    for (int m = 0; m < 4; m++) {
        int c = 16 * m + lr;
#pragma unroll
        for (int j = 0; j < 8; j++) {
            int kk = 8 * g + j;
            float w = (kk < 27) ? ldsW[c * 27 + kk] : 0.0f;
            w1A[m].s[j] = f2bf(w);
        }
    }
    BF8 w2dx[3][2];                 // GEMM2 A: rows p=(dz,dy)<9, t=3p+dx
#pragma unroll
    for (int dx = 0; dx < 3; dx++)
#pragma unroll
        for (int ks = 0; ks < 2; ks++)
#pragma unroll
            for (int j = 0; j < 8; j++) {
                int ch = 32 * ks + 8 * g + j;
                float w = (lr < NP) ? ldsW[1728 + ch * 27 + 3 * lr + dx] : 0.0f;
                w2dx[dx][ks].s[j] = f2bf(w);
            }
    float bias[4][4];               // b1 for D rows c = 16m+4g+r (exact f32)
#pragma unroll
    for (int m = 0; m < 4; m++)
#pragma unroll
        for (int r = 0; r < 4; r++) bias[m][r] = ldsW[3456 + 16 * m + 4 * g + r];

    // ---- per-lane tap offsets (k>=27: any valid cell; A rows are zero) ----
    int tapoff[8];
#pragma unroll
    for (int j = 0; j < 8; j++) {
        int kk = 8 * g + j;
        int kc = kk < 27 ? kk : 0;
        int dz = kc / 9, ry = kc - dz * 9;
        int dy = ry / 3, dxx = ry - dy * 3;
        tapoff[j] = dz * 396 + dy * 66 + dxx;
    }

    __syncthreads();    // weights region dead -> Y-line buffers

    u32* myY = &Ylds[wv][0];

    for (int li = 0; li < 4; li++) {
        int l = wv * 4 + li;
        int zl = l >> 2, yl = l & 3;
        int linebase = (zl * 6 + yl) * 66 + lr;
        int vbase = ((z0 + zl) << 12) + ((y0 + yl) << 6);

        // zero pad rows 0 (x=-1) and 65 (x=64)
        myY[(lane < 32 ? 0 : 65 * YSTRIDE) + (lane & 31)] = 0;

        // ---- GEMM1 phase: fill Y-line rows 1..64 ----
        for (int xt = 0; xt < 4; xt++) {
            int x0 = xt * 16;
            BF8 xB;
#pragma unroll
            for (int j = 0; j < 8; j++)
                xB.s[j] = halo[linebase + x0 + tapoff[j]];

            f32x4 yac[4];
#pragma unroll
            for (int m = 0; m < 4; m++) {
                f32x4 c0;
                c0[0] = bias[m][0]; c0[1] = bias[m][1];
                c0[2] = bias[m][2]; c0[3] = bias[m][3];
                yac[m] = __builtin_amdgcn_mfma_f32_16x16x32_bf16(
                    w1A[m].v, xB.v, c0, 0, 0, 0);
            }

            int rx = x0 + lr + 1;     // buffer row for x = x0+lr
#pragma unroll
            for (int m = 0; m < 4; m++) {
                float a0 = fmaxf(yac[m][0], 0.f), a1 = fmaxf(yac[m][1], 0.f);
                float a2 = fmaxf(yac[m][2], 0.f), a3 = fmaxf(yac[m][3], 0.f);
                u32 h01 = cvt_pk_bf16(a0, a1);
                u32 h23 = cvt_pk_bf16(a2, a3);
                *(U64*)&myY[rx * YSTRIDE + 8 * m + 2 * g] =
                    (U64)h01 | ((U64)h23 << 32);
            }
        }

        asm volatile("" ::: "memory");   // order line writes vs reads

        // ---- GEMM2 phase: zrow = sum_dx W2dx @ Y(shifted) ----
        for (int xt = 0; xt < 4; xt++) {
            int x0 = xt * 16;
            f32x4 zac = f32x4{0.f, 0.f, 0.f, 0.f};
#pragma unroll
            for (int dx = 0; dx < 3; dx++) {
                int rbase = (x0 + lr + dx) * YSTRIDE;
#pragma unroll
                for (int ks = 0; ks < 2; ks++) {
                    bf16x8 yB = *(const bf16x8*)&myY[rbase + 16 * ks + 4 * g];
                    zac = __builtin_amdgcn_mfma_f32_16x16x32_bf16(
                        w2dx[dx][ks].v, yB, zac, 0, 0, 0);
                }
            }

            int vg = vbase + x0 + lr;
#pragma unroll
            for (int r = 0; r < 4; r++) {
                int p = 4 * g + r;
                if (p < NP)
                    zb[(size_t)p * GV + vg] = f2bf(zac[r]);
            }
        }

        asm volatile("" ::: "memory");   // line buffer reused next li
    }
}

// ---------------------------------------------------------------------------
// convB: x2(v) = relu(b2 + sum_p zrow_p(z+dz-1, y+dy-1, x)) — 9 coalesced taps
// ---------------------------------------------------------------------------
__global__ __launch_bounds__(256) void convB_kernel(
    const u16* __restrict__ zbuf,
    float* __restrict__ xout,
    const float* __restrict__ b2)
{
    int b = blockIdx.y;
    const u16* zb = zbuf + (size_t)b * (NP * (size_t)GV);
    float* xo = xout + (size_t)b * GV;

    int v  = blockIdx.x * 256 + threadIdx.x;
    int zc = v >> 12, yc = (v >> 6) & 63, xc = v & 63;
    float acc = b2[0];
#pragma unroll
    for (int dz = 0; dz < 3; dz++)
#pragma unroll
    for (int dy = 0; dy < 3; dy++) {
        int p = dz * 3 + dy;
        int zz = zc + dz - 1, yy = yc + dy - 1;
        bool ok = ((unsigned)zz < (unsigned)G) & ((unsigned)yy < (unsigned)G);
        if (ok) acc += bf2f(zb[(size_t)p * GV + (zz << 12) + (yy << 6) + xc]);
    }
    xo[v] = fmaxf(acc, 0.0f);
}

// ---------------------------------------------------------------------------
// fc1: unchanged (R10-proven)
// ---------------------------------------------------------------------------
__global__ __launch_bounds__(256) void fc1_kernel(
    const float* __restrict__ W, const float* __restrict__ x,
    float* __restrict__ pacc)
{
    int jt = blockIdx.x;            // 0..31
    int vc = blockIdx.y;            // 0..63
    int tid = threadIdx.x;
    int j0 = jt * 8;
    size_t v0 = (size_t)vc * 4096;

    const f32x4* Wp[8];
#pragma unroll
    for (int jj = 0; jj < 8; jj++)
        Wp[jj] = reinterpret_cast<const f32x4*>(W + (size_t)(j0 + jj) * GV + v0);
    const f32x4* Xp[NB];
#pragma unroll
    for (int b = 0; b < NB; b++)
        Xp[b] = reinterpret_cast<const f32x4*>(x + (size_t)b * GV + v0);

    float acc[8][NB];
#pragma unroll
    for (int jj = 0; jj < 8; jj++)
#pragma unroll
        for (int b = 0; b < NB; b++) acc[jj][b] = 0.0f;

    for (int i = 0; i < 4; i++) {
        int e = i * 256 + tid;
        f32x4 wvv[8];
#pragma unroll
        for (int jj = 0; jj < 8; jj++)
            wvv[jj] = __builtin_nontemporal_load(&Wp[jj][e]);
        f32x4 xv[NB];
#pragma unroll
        for (int b = 0; b < NB; b++) xv[b] = Xp[b][e];
#pragma unroll
        for (int b = 0; b < NB; b++) {
#pragma unroll
            for (int jj = 0; jj < 8; jj++) {
                acc[jj][b] = fmaf(wvv[jj][0], xv[b][0], acc[jj][b]);
                acc[jj][b] = fmaf(wvv[jj][1], xv[b][1], acc[jj][b]);
                acc[jj][b] = fmaf(wvv[jj][2], xv[b][2], acc[jj][b]);
                acc[jj][b] = fmaf(wvv[jj][3], xv[b][3], acc[jj][b]);
            }
        }
    }

    __shared__ float sacc[256][36];
    __shared__ float p2[8][40];
#pragma unroll
    for (int pass = 0; pass < 2; pass++) {
        if (pass > 0) __syncthreads();
        float4* row = reinterpret_cast<float4*>(&sacc[tid][0]);
#pragma unroll
        for (int jj = 0; jj < 4; jj++) {
            int js = pass * 4 + jj;
            row[jj * 2 + 0] = make_float4(acc[js][0], acc[js][1], acc[js][2], acc[js][3]);
            row[jj * 2 + 1] = make_float4(acc[js][4], acc[js][5], acc[js][6], acc[js][7]);
        }
        __syncthreads();
        {
            int o = tid & 31, gg = tid >> 5;
            float s = 0.0f;
#pragma unroll
            for (int k = 0; k < 32; k++) s += sacc[gg * 32 + k][o];
            p2[gg][o] = s;
        }
        __syncthreads();
        if (tid < 32) {
            float s = 0.0f;
#pragma unroll
            for (int gg = 0; gg < 8; gg++) s += p2[gg][tid];
            int jj = tid >> 3, b = tid & 7;
            pacc[((size_t)b * 64 + vc) * 256 + (j0 + pass * 4 + jj)] = s;
        }
    }
}

// ---------------------------------------------------------------------------
#define BPB 32
#define IDXM 0x3FFFFu

// topk1 also zeros its slice of the points output
__global__ __launch_bounds__(256) void topk1_kernel(
    const float* __restrict__ bnd, const float* __restrict__ noise,
    U64* __restrict__ cand, float4* __restrict__ pts_out)
{
    int blk = blockIdx.x;
    int b   = blockIdx.y;
    int tid = threadIdx.x;
    int vbase = blk * (GV / BPB);

    float4* zp = pts_out + ((size_t)b * GV + vbase) / 4;
#pragma unroll
    for (int i = 0; i < 8; i++)
        zp[i * 256 + tid] = make_float4(0.f, 0.f, 0.f, 0.f);

    const float* bd = bnd + (size_t)b * GV + vbase;
    const float* nz = noise + (size_t)b * GV + vbase;

    U64 top[10];
#pragma unroll
    for (int k = 0; k < 10; k++) top[k] = 0ull;

    for (int i = 0; i < (GV / BPB) / 256; i++) {
        int e = i * 256 + tid;
        float bv = bd[e];
        float s  = nz[e];
        U64 p = (bv > 0.5f) ? 0ull
              : ((((U64)__float_as_uint(s)) << 32) |
                 (IDXM - (unsigned)(vbase + e)));
        if (p > top[9]) {
#pragma unroll
            for (int k = 0; k < 10; k++) {
                U64 mx = p > top[k] ? p : top[k];
                U64 mn = p > top[k] ? top[k] : p;
                top[k] = mx; p = mn;
            }
        }
    }

    __shared__ U64 lcand[256 * 10];
    __shared__ U64 rv[256];
    __shared__ int rp[256];
#pragma unroll
    for (int k = 0; k < 10; k++) lcand[tid * 10 + k] = top[k];
    __syncthreads();

    for (int pass = 0; pass < 10; pass++) {
        U64 bv = 0; int bp = 0;
        for (int i = tid; i < 2560; i += 256) {
            U64 xv = lcand[i];
            if (xv > bv) { bv = xv; bp = i; }
        }
        rv[tid] = bv; rp[tid] = bp;
        __syncthreads();
        for (int off = 128; off > 0; off >>= 1) {
            if (tid < off) {
                if (rv[tid + off] > rv[tid]) { rv[tid] = rv[tid + off]; rp[tid] = rp[tid + off]; }
            }
            __syncthreads();
        }
        if (tid == 0) {
            cand[((size_t)b * BPB + blk) * 10 + pass] = rv[0];
            lcand[rp[0]] = 0ull;
        }
        __syncthreads();
    }
}

// blocks 0..7: topk2 per batch; block 8: fc_final
__global__ __launch_bounds__(256) void finalize_kernel(
    const U64* __restrict__ cand, float* __restrict__ pts,
    const float* __restrict__ pacc, const float* __restrict__ fc1_b,
    const float* __restrict__ fc2_w, const float* __restrict__ fc2_b,
    float* __restrict__ prob)
{
    int tid = threadIdx.x;

    if (blockIdx.x < 8) {
        int b = blockIdx.x;
        __shared__ U64 lc[BPB * 10];
        __shared__ U64 rv[256];
        __shared__ int rp[256];
        __shared__ int widx[10];
        for (int i = tid; i < BPB * 10; i += 256) lc[i] = cand[(size_t)b * BPB * 10 + i];
        __syncthreads();

        for (int pass = 0; pass < 10; pass++) {
            U64 bv = 0; int bp = 0;
            for (int i = tid; i < BPB * 10; i += 256) {
                U64 xv = lc[i];
                if (xv > bv) { bv = xv; bp = i; }
            }
            rv[tid] = bv; rp[tid] = bp;
            __syncthreads();
            for (int off = 128; off > 0; off >>= 1) {
                if (tid < off) {
                    if (rv[tid + off] > rv[tid]) { rv[tid] = rv[tid + off]; rp[tid] = rp[tid + off]; }
                }
                __syncthreads();
            }
            if (tid == 0) { widx[pass] = (int)(IDXM - (u32)(rv[0] & 0xffffffffu)); lc[rp[0]] = 0ull; }
            __syncthreads();
        }
        if (tid < 10) pts[(size_t)b * GV + widx[tid]] = 1.0f;
    } else {
        int j = tid;
        float h[NB];
#pragma unroll
        for (int b = 0; b < NB; b++) h[b] = 0.0f;
        for (int c = 0; c < 64; c++) {
#pragma unroll
            for (int b = 0; b < NB; b++)
                h[b] += pacc[((size_t)b * 64 + c) * 256 + j];
        }
        float w2j = fc2_w[j];
        float contrib[NB];
#pragma unroll
        for (int b = 0; b < NB; b++)
            contrib[b] = fmaxf(h[b] + fc1_b[j], 0.0f) * w2j;

        int lane = j & 63, wid = j >> 6;
#pragma unroll
        for (int b = 0; b < NB; b++)
#pragma unroll
            for (int off = 32; off > 0; off >>= 1)
                contrib[b] += __shfl_down(contrib[b], off, 64);

        __shared__ float sred[4][NB];
        if (lane == 0) {
#pragma unroll
            for (int b = 0; b < NB; b++) sred[wid][b] = contrib[b];
        }
        __syncthreads();
        if (j < NB) {
            float t = sred[0][j] + sred[1][j] + sred[2][j] + sred[3][j] + fc2_b[0];
            prob[j] = 100.0f / (1.0f + expf(-t));
        }
    }
}

// ---------------------------------------------------------------------------
extern "C" void kernel_launch(void* const* d_in, const int* in_sizes, int n_in,
                              void* d_out, int out_size, void* d_ws, size_t ws_size,
                              hipStream_t stream)
{
    const float* bnd   = (const float*)d_in[0];
    const float* w1    = (const float*)d_in[1];
    const float* b1    = (const float*)d_in[2];
    const float* w2    = (const float*)d_in[3];
    const float* b2    = (const float*)d_in[4];
    const float* fw1   = (const float*)d_in[5];
    const float* fb1   = (const float*)d_in[6];
    const float* fw2   = (const float*)d_in[7];
    const float* fb2   = (const float*)d_in[8];
    const float* noise = (const float*)d_in[9];

    float* out = (float*)d_out;
    char* ws = (char*)d_ws;

    const size_t xbuf_off = 0;                                 // 8 MB
    const size_t pacc_off = xbuf_off + (size_t)NB * GV * 4;    // 512 KB
    const size_t cand_off = pacc_off + (size_t)NB * 64 * 256 * 4;
    const size_t zbuf_off = cand_off + (size_t)NB * BPB * 10 * 8;

    float* xbuf = (float*)(ws + xbuf_off);
    float* pacc = (float*)(ws + pacc_off);
    U64*   cand = (U64*)(ws + cand_off);
    u16*   zbuf = (u16*)(ws + zbuf_off);                       // 8 x 4.5 MB

    dim3 gA(256, NB);       // (4z x 4y) boxes x 8 batches
    convA_mfma_kernel<<<gA, 256, 0, stream>>>(bnd, w1, b1, w2, zbuf);

    dim3 gB(GV / 256, NB);
    convB_kernel<<<gB, 256, 0, stream>>>(zbuf, xbuf, b2);

    dim3 gfc(32, 64);
    fc1_kernel<<<gfc, 256, 0, stream>>>(fw1, xbuf, pacc);

    dim3 gt(BPB, NB);
    topk1_kernel<<<gt, 256, 0, stream>>>(bnd, noise, cand, (float4*)out);

    finalize_kernel<<<9, 256, 0, stream>>>(cand, out, pacc, fb1, fw2, fb2,
                                           out + (size_t)NB * GV);
}

// Round 13
// 172.190 us; speedup vs baseline: 1.5644x; 1.0706x over previous
//
#include <hip/hip_runtime.h>
#include <math.h>

#define G 64
#define GV (G*G*G)      // 262144
#define NB 8
#define NP 9            // zrow planes (dz,dy)

typedef unsigned short u16;
typedef unsigned int u32;
typedef unsigned long long U64;
typedef __bf16 bf16x8 __attribute__((ext_vector_type(8)));
typedef float f32x4 __attribute__((ext_vector_type(4)));

union BF8 { u16 s[8]; bf16x8 v; };

__device__ __forceinline__ float bf2f(u16 h) {
    union { u32 u; float f; } c; c.u = ((u32)h) << 16; return c.f;
}
__device__ __forceinline__ u16 f2bf(float f) {
    union { float f; u32 u; } c; c.f = f;
    u32 u = c.u;
    return (u16)((u + 0x7fffu + ((u >> 16) & 1u)) >> 16);   // RNE
}
__device__ __forceinline__ u32 cvt_pk_bf16(float lo, float hi) {
    u32 r;
    asm volatile("v_cvt_pk_bf16_f32 %0, %1, %2" : "=v"(r) : "v"(lo), "v"(hi));
    return r;
}

#define YSTRIDE 36   // u32 per x-row; stride%32=4 banks -> free 2-way conflict

// ---------------------------------------------------------------------------
// convA via MFMA, x-taps folded (R12-proven, unchanged)
// ---------------------------------------------------------------------------
__global__ __launch_bounds__(256) void convA_mfma_kernel(
    const float* __restrict__ bnd,
    const float* __restrict__ w1, const float* __restrict__ b1,
    const float* __restrict__ w2,
    u16* __restrict__ zbuf)
{
    int b = blockIdx.y;
    const float* bd = bnd + (size_t)b * GV;
    u16* zb = zbuf + (size_t)b * (NP * (size_t)GV);

    __shared__ __align__(16) u16 halo[2378];          // 6*6*66 + pad
    __shared__ __align__(16) u32 Ylds[4][66 * YSTRIDE];

    int tid = threadIdx.x;
    int z0 = (blockIdx.x >> 4) * 4, y0 = (blockIdx.x & 15) * 4;

    // ---- coalesced weight stage (into Ylds region, dead until GEMM phase) ----
    {
        float* ldsW = (float*)&Ylds[0][0];
        for (int i = tid; i < 3520; i += 256) {
            float v;
            if (i < 1728)      v = w1[i];
            else if (i < 3456) v = w2[i - 1728];
            else               v = b1[i - 3456];
            ldsW[i] = v;
        }
    }

    // ---- halo fill (bf16 bit patterns 0x3F80 / 0) ----
    for (int i = tid; i < 2378; i += 256) {
        u16 hval = 0;
        if (i < 2376) {
            int hz = i / 396, rem = i - hz * 396;
            int hy = rem / 66, hx = rem - hy * 66;
            int gz = z0 + hz - 1, gy = y0 + hy - 1, gx = hx - 1;
            if (((unsigned)gz < (unsigned)G) & ((unsigned)gy < (unsigned)G) &
                ((unsigned)gx < (unsigned)G)) {
                float f = bd[(gz << 12) + (gy << 6) + gx];
                hval = (f > 0.5f) ? (u16)0x3F80 : (u16)0;
            }
        }
        halo[i] = hval;
    }

    __syncthreads();

    int wv = tid >> 6, lane = tid & 63;
    int g = lane >> 4, lr = lane & 15;

    // ---- fragment build from LDS (bf16 weights) ----
    const float* ldsW = (const float*)&Ylds[0][0];
    BF8 w1A[4];                     // GEMM1 A: 4 c-tiles, K=27 pad 32
#pragma unroll
    for (int m = 0; m < 4; m++) {
        int c = 16 * m + lr;
#pragma unroll
        for (int j = 0; j < 8; j++) {
            int kk = 8 * g + j;
            float w = (kk < 27) ? ldsW[c * 27 + kk] : 0.0f;
            w1A[m].s[j] = f2bf(w);
        }
    }
    BF8 w2dx[3][2];                 // GEMM2 A: rows p=(dz,dy)<9, t=3p+dx
#pragma unroll
    for (int dx = 0; dx < 3; dx++)
#pragma unroll
        for (int ks = 0; ks < 2; ks++)
#pragma unroll
            for (int j = 0; j < 8; j++) {
                int ch = 32 * ks + 8 * g + j;
                float w = (lr < NP) ? ldsW[1728 + ch * 27 + 3 * lr + dx] : 0.0f;
                w2dx[dx][ks].s[j] = f2bf(w);
            }
    float bias[4][4];               // b1 for D rows c = 16m+4g+r (exact f32)
#pragma unroll
    for (int m = 0; m < 4; m++)
#pragma unroll
        for (int r = 0; r < 4; r++) bias[m][r] = ldsW[3456 + 16 * m + 4 * g + r];

    // ---- per-lane tap offsets (k>=27: any valid cell; A rows are zero) ----
    int tapoff[8];
#pragma unroll
    for (int j = 0; j < 8; j++) {
        int kk = 8 * g + j;
        int kc = kk < 27 ? kk : 0;
        int dz = kc / 9, ry = kc - dz * 9;
        int dy = ry / 3, dxx = ry - dy * 3;
        tapoff[j] = dz * 396 + dy * 66 + dxx;
    }

    __syncthreads();    // weights region dead -> Y-line buffers

    u32* myY = &Ylds[wv][0];

    for (int li = 0; li < 4; li++) {
        int l = wv * 4 + li;
        int zl = l >> 2, yl = l & 3;
        int linebase = (zl * 6 + yl) * 66 + lr;
        int vbase = ((z0 + zl) << 12) + ((y0 + yl) << 6);

        // zero pad rows 0 (x=-1) and 65 (x=64)
        myY[(lane < 32 ? 0 : 65 * YSTRIDE) + (lane & 31)] = 0;

        // ---- GEMM1 phase: fill Y-line rows 1..64 ----
        for (int xt = 0; xt < 4; xt++) {
            int x0 = xt * 16;
            BF8 xB;
#pragma unroll
            for (int j = 0; j < 8; j++)
                xB.s[j] = halo[linebase + x0 + tapoff[j]];

            f32x4 yac[4];
#pragma unroll
            for (int m = 0; m < 4; m++) {
                f32x4 c0;
                c0[0] = bias[m][0]; c0[1] = bias[m][1];
                c0[2] = bias[m][2]; c0[3] = bias[m][3];
                yac[m] = __builtin_amdgcn_mfma_f32_16x16x32_bf16(
                    w1A[m].v, xB.v, c0, 0, 0, 0);
            }

            int rx = x0 + lr + 1;     // buffer row for x = x0+lr
#pragma unroll
            for (int m = 0; m < 4; m++) {
                float a0 = fmaxf(yac[m][0], 0.f), a1 = fmaxf(yac[m][1], 0.f);
                float a2 = fmaxf(yac[m][2], 0.f), a3 = fmaxf(yac[m][3], 0.f);
                u32 h01 = cvt_pk_bf16(a0, a1);
                u32 h23 = cvt_pk_bf16(a2, a3);
                *(U64*)&myY[rx * YSTRIDE + 8 * m + 2 * g] =
                    (U64)h01 | ((U64)h23 << 32);
            }
        }

        asm volatile("" ::: "memory");   // order line writes vs reads

        // ---- GEMM2 phase: zrow = sum_dx W2dx @ Y(shifted) ----
        for (int xt = 0; xt < 4; xt++) {
            int x0 = xt * 16;
            f32x4 zac = f32x4{0.f, 0.f, 0.f, 0.f};
#pragma unroll
            for (int dx = 0; dx < 3; dx++) {
                int rbase = (x0 + lr + dx) * YSTRIDE;
#pragma unroll
                for (int ks = 0; ks < 2; ks++) {
                    bf16x8 yB = *(const bf16x8*)&myY[rbase + 16 * ks + 4 * g];
                    zac = __builtin_amdgcn_mfma_f32_16x16x32_bf16(
                        w2dx[dx][ks].v, yB, zac, 0, 0, 0);
                }
            }

            int vg = vbase + x0 + lr;
#pragma unroll
            for (int r = 0; r < 4; r++) {
                int p = 4 * g + r;
                if (p < NP)
                    zb[(size_t)p * GV + vg] = f2bf(zac[r]);
            }
        }

        asm volatile("" ::: "memory");   // line buffer reused next li
    }
}

// ---------------------------------------------------------------------------
#define BPB 32
#define IDXM 0x3FFFFu

// Merged kernel: blocks 0..255 = topk1 (also zeros points out);
//                blocks 256..8447 = convB (9-tap zrow stencil)
// ---------------------------------------------------------------------------
__global__ __launch_bounds__(256) void convB_topk_kernel(
    const u16* __restrict__ zbuf, float* __restrict__ xout,
    const float* __restrict__ b2,
    const float* __restrict__ bnd, const float* __restrict__ noise,
    U64* __restrict__ cand, float4* __restrict__ pts_out)
{
    __shared__ U64 lcand[256 * 10];
    __shared__ U64 rv[256];
    __shared__ int rp[256];

    int tid = threadIdx.x;

    if (blockIdx.x >= 256) {
        // ---- convB ----
        int r = blockIdx.x - 256;
        int vblk = r & 1023, b = r >> 10;
        const u16* zb = zbuf + (size_t)b * (NP * (size_t)GV);
        float* xo = xout + (size_t)b * GV;

        int v  = vblk * 256 + tid;
        int zc = v >> 12, yc = (v >> 6) & 63, xc = v & 63;
        float acc = b2[0];
#pragma unroll
        for (int dz = 0; dz < 3; dz++)
#pragma unroll
        for (int dy = 0; dy < 3; dy++) {
            int p = dz * 3 + dy;
            int zz = zc + dz - 1, yy = yc + dy - 1;
            bool ok = ((unsigned)zz < (unsigned)G) & ((unsigned)yy < (unsigned)G);
            if (ok) acc += bf2f(zb[(size_t)p * GV + (zz << 12) + (yy << 6) + xc]);
        }
        xo[v] = fmaxf(acc, 0.0f);
        return;
    }

    // ---- topk1 ----
    int blk = blockIdx.x & 31;
    int b   = blockIdx.x >> 5;
    int vbase = blk * (GV / BPB);

    float4* zp = pts_out + ((size_t)b * GV + vbase) / 4;
#pragma unroll
    for (int i = 0; i < 8; i++)
        zp[i * 256 + tid] = make_float4(0.f, 0.f, 0.f, 0.f);

    const float* bd = bnd + (size_t)b * GV + vbase;
    const float* nz = noise + (size_t)b * GV + vbase;

    U64 top[10];
#pragma unroll
    for (int k = 0; k < 10; k++) top[k] = 0ull;

    for (int i = 0; i < (GV / BPB) / 256; i++) {
        int e = i * 256 + tid;
        float bv = bd[e];
        float s  = nz[e];
        U64 p = (bv > 0.5f) ? 0ull
              : ((((U64)__float_as_uint(s)) << 32) |
                 (IDXM - (unsigned)(vbase + e)));
        if (p > top[9]) {
#pragma unroll
            for (int k = 0; k < 10; k++) {
                U64 mx = p > top[k] ? p : top[k];
                U64 mn = p > top[k] ? top[k] : p;
                top[k] = mx; p = mn;
            }
        }
    }

#pragma unroll
    for (int k = 0; k < 10; k++) lcand[tid * 10 + k] = top[k];
    __syncthreads();

    for (int pass = 0; pass < 10; pass++) {
        U64 bv = 0; int bp = 0;
        for (int i = tid; i < 2560; i += 256) {
            U64 xv = lcand[i];
            if (xv > bv) { bv = xv; bp = i; }
        }
        rv[tid] = bv; rp[tid] = bp;
        __syncthreads();
        for (int off = 128; off > 0; off >>= 1) {
            if (tid < off) {
                if (rv[tid + off] > rv[tid]) { rv[tid] = rv[tid + off]; rp[tid] = rp[tid + off]; }
            }
            __syncthreads();
        }
        if (tid == 0) {
            cand[((size_t)b * BPB + blk) * 10 + pass] = rv[0];
            lcand[rp[0]] = 0ull;
        }
        __syncthreads();
    }
}

// ---------------------------------------------------------------------------
// fc1 with XCD-aware remap: XCD k handles vc in [8k, 8k+8) only ->
// its x window (1 MB) stays resident in the per-XCD L2.
// ---------------------------------------------------------------------------
__global__ __launch_bounds__(256) void fc1_kernel(
    const float* __restrict__ W, const float* __restrict__ x,
    float* __restrict__ pacc)
{
    int bid = blockIdx.x;           // 0..2047
    int xcd  = bid & 7;
    int slot = bid >> 3;            // 0..255
    int vc = (xcd << 3) | (slot >> 5);   // 0..63
    int jt = slot & 31;             // 0..31
    int tid = threadIdx.x;
    int j0 = jt * 8;
    size_t v0 = (size_t)vc * 4096;

    const f32x4* Wp[8];
#pragma unroll
    for (int jj = 0; jj < 8; jj++)
        Wp[jj] = reinterpret_cast<const f32x4*>(W + (size_t)(j0 + jj) * GV + v0);
    const f32x4* Xp[NB];
#pragma unroll
    for (int b = 0; b < NB; b++)
        Xp[b] = reinterpret_cast<const f32x4*>(x + (size_t)b * GV + v0);

    float acc[8][NB];
#pragma unroll
    for (int jj = 0; jj < 8; jj++)
#pragma unroll
        for (int b = 0; b < NB; b++) acc[jj][b] = 0.0f;

    for (int i = 0; i < 4; i++) {
        int e = i * 256 + tid;
        f32x4 wvv[8];
#pragma unroll
        for (int jj = 0; jj < 8; jj++)
            wvv[jj] = __builtin_nontemporal_load(&Wp[jj][e]);
        f32x4 xv[NB];
#pragma unroll
        for (int b = 0; b < NB; b++) xv[b] = Xp[b][e];
#pragma unroll
        for (int b = 0; b < NB; b++) {
#pragma unroll
            for (int jj = 0; jj < 8; jj++) {
                acc[jj][b] = fmaf(wvv[jj][0], xv[b][0], acc[jj][b]);
                acc[jj][b] = fmaf(wvv[jj][1], xv[b][1], acc[jj][b]);
                acc[jj][b] = fmaf(wvv[jj][2], xv[b][2], acc[jj][b]);
                acc[jj][b] = fmaf(wvv[jj][3], xv[b][3], acc[jj][b]);
            }
        }
    }

    __shared__ float sacc[256][36];
    __shared__ float p2[8][40];
#pragma unroll
    for (int pass = 0; pass < 2; pass++) {
        if (pass > 0) __syncthreads();
        float4* row = reinterpret_cast<float4*>(&sacc[tid][0]);
#pragma unroll
        for (int jj = 0; jj < 4; jj++) {
            int js = pass * 4 + jj;
            row[jj * 2 + 0] = make_float4(acc[js][0], acc[js][1], acc[js][2], acc[js][3]);
            row[jj * 2 + 1] = make_float4(acc[js][4], acc[js][5], acc[js][6], acc[js][7]);
        }
        __syncthreads();
        {
            int o = tid & 31, gg = tid >> 5;
            float s = 0.0f;
#pragma unroll
            for (int k = 0; k < 32; k++) s += sacc[gg * 32 + k][o];
            p2[gg][o] = s;
        }
        __syncthreads();
        if (tid < 32) {
            float s = 0.0f;
#pragma unroll
            for (int gg = 0; gg < 8; gg++) s += p2[gg][tid];
            int jj = tid >> 3, b = tid & 7;
            pacc[((size_t)b * 64 + vc) * 256 + (j0 + pass * 4 + jj)] = s;
        }
    }
}

// ---------------------------------------------------------------------------
// finalize: blocks 0..7 topk2 per batch; block 8 fc_final
// ---------------------------------------------------------------------------
__global__ __launch_bounds__(256) void finalize_kernel(
    const U64* __restrict__ cand, float* __restrict__ pts,
    const float* __restrict__ pacc, const float* __restrict__ fc1_b,
    const float* __restrict__ fc2_w, const float* __restrict__ fc2_b,
    float* __restrict__ prob)
{
    int tid = threadIdx.x;

    if (blockIdx.x < 8) {
        int b = blockIdx.x;
        __shared__ U64 lc[BPB * 10];
        __shared__ U64 rv[256];
        __shared__ int rp[256];
        __shared__ int widx[10];
        for (int i = tid; i < BPB * 10; i += 256) lc[i] = cand[(size_t)b * BPB * 10 + i];
        __syncthreads();

        for (int pass = 0; pass < 10; pass++) {
            U64 bv = 0; int bp = 0;
            for (int i = tid; i < BPB * 10; i += 256) {
                U64 xv = lc[i];
                if (xv > bv) { bv = xv; bp = i; }
            }
            rv[tid] = bv; rp[tid] = bp;
            __syncthreads();
            for (int off = 128; off > 0; off >>= 1) {
                if (tid < off) {
                    if (rv[tid + off] > rv[tid]) { rv[tid] = rv[tid + off]; rp[tid] = rp[tid + off]; }
                }
                __syncthreads();
            }
            if (tid == 0) { widx[pass] = (int)(IDXM - (u32)(rv[0] & 0xffffffffu)); lc[rp[0]] = 0ull; }
            __syncthreads();
        }
        if (tid < 10) pts[(size_t)b * GV + widx[tid]] = 1.0f;
    } else {
        int j = tid;
        float h[NB];
#pragma unroll
        for (int b = 0; b < NB; b++) h[b] = 0.0f;
        for (int c = 0; c < 64; c++) {
#pragma unroll
            for (int b = 0; b < NB; b++)
                h[b] += pacc[((size_t)b * 64 + c) * 256 + j];
        }
        float w2j = fc2_w[j];
        float contrib[NB];
#pragma unroll
        for (int b = 0; b < NB; b++)
            contrib[b] = fmaxf(h[b] + fc1_b[j], 0.0f) * w2j;

        int lane = j & 63, wid = j >> 6;
#pragma unroll
        for (int b = 0; b < NB; b++)
#pragma unroll
            for (int off = 32; off > 0; off >>= 1)
                contrib[b] += __shfl_down(contrib[b], off, 64);

        __shared__ float sred[4][NB];
        if (lane == 0) {
#pragma unroll
            for (int b = 0; b < NB; b++) sred[wid][b] = contrib[b];
        }
        __syncthreads();
        if (j < NB) {
            float t = sred[0][j] + sred[1][j] + sred[2][j] + sred[3][j] + fc2_b[0];
            prob[j] = 100.0f / (1.0f + expf(-t));
        }
    }
}

// ---------------------------------------------------------------------------
extern "C" void kernel_launch(void* const* d_in, const int* in_sizes, int n_in,
                              void* d_out, int out_size, void* d_ws, size_t ws_size,
                              hipStream_t stream)
{
    const float* bnd   = (const float*)d_in[0];
    const float* w1    = (const float*)d_in[1];
    const float* b1    = (const float*)d_in[2];
    const float* w2    = (const float*)d_in[3];
    const float* b2    = (const float*)d_in[4];
    const float* fw1   = (const float*)d_in[5];
    const float* fb1   = (const float*)d_in[6];
    const float* fw2   = (const float*)d_in[7];
    const float* fb2   = (const float*)d_in[8];
    const float* noise = (const float*)d_in[9];

    float* out = (float*)d_out;
    char* ws = (char*)d_ws;

    const size_t xbuf_off = 0;                                 // 8 MB
    const size_t pacc_off = xbuf_off + (size_t)NB * GV * 4;    // 512 KB
    const size_t cand_off = pacc_off + (size_t)NB * 64 * 256 * 4;
    const size_t zbuf_off = cand_off + (size_t)NB * BPB * 10 * 8;

    float* xbuf = (float*)(ws + xbuf_off);
    float* pacc = (float*)(ws + pacc_off);
    U64*   cand = (U64*)(ws + cand_off);
    u16*   zbuf = (u16*)(ws + zbuf_off);                       // 8 x 4.5 MB

    dim3 gA(256, NB);       // (4z x 4y) boxes x 8 batches
    convA_mfma_kernel<<<gA, 256, 0, stream>>>(bnd, w1, b1, w2, zbuf);

    // merged: topk1 (blocks 0..255) + convB (blocks 256..8447)
    convB_topk_kernel<<<8448, 256, 0, stream>>>(zbuf, xbuf, b2, bnd, noise,
                                                cand, (float4*)out);

    fc1_kernel<<<2048, 256, 0, stream>>>(fw1, xbuf, pacc);

    finalize_kernel<<<9, 256, 0, stream>>>(cand, out, pacc, fb1, fw2, fb2,
                                           out + (size_t)NB * GV);
}

// Round 14
// 164.932 us; speedup vs baseline: 1.6333x; 1.0440x over previous
//
#include <hip/hip_runtime.h>
#include <math.h>

#define G 64
#define GV (G*G*G)      // 262144
#define NB 8
#define NP 9            // zrow planes (dz,dy)

typedef unsigned short u16;
typedef unsigned int u32;
typedef unsigned long long U64;
typedef __bf16 bf16x8 __attribute__((ext_vector_type(8)));
typedef float f32x4 __attribute__((ext_vector_type(4)));

union BF8 { u16 s[8]; bf16x8 v; };

__device__ __forceinline__ float bf2f(u16 h) {
    union { u32 u; float f; } c; c.u = ((u32)h) << 16; return c.f;
}
__device__ __forceinline__ u16 f2bf(float f) {
    union { float f; u32 u; } c; c.f = f;
    u32 u = c.u;
    return (u16)((u + 0x7fffu + ((u >> 16) & 1u)) >> 16);   // RNE
}
__device__ __forceinline__ u32 cvt_pk_bf16(float lo, float hi) {
    u32 r;
    asm volatile("v_cvt_pk_bf16_f32 %0, %1, %2" : "=v"(r) : "v"(lo), "v"(hi));
    return r;
}

#define YSTRIDE 36   // u32 per x-row; stride%32=4 banks -> free 2-way conflict
#define BPB 32
#define IDXM 0x3FFFFu
#define POOLB 42784  // union: convA (4768 halo + 38016 Ylds) | topk (23552)

// ---------------------------------------------------------------------------
// Merged dispatch 1: blocks 0..255 = topk1 (indep of convA; zeroes points,
// writes cand) — overlaps under convA's compute. blocks 256..2303 = convA.
// ---------------------------------------------------------------------------
__global__ __launch_bounds__(256) void convA_topk_kernel(
    const float* __restrict__ bnd,
    const float* __restrict__ w1, const float* __restrict__ b1,
    const float* __restrict__ w2,
    u16* __restrict__ zbuf,
    const float* __restrict__ noise,
    U64* __restrict__ cand, float4* __restrict__ pts_out)
{
    __shared__ __align__(16) char pool[POOLB];
    int tid = threadIdx.x;

    if (blockIdx.x < 256) {
        // ================= topk1 (also zeros points output) ================
        int blk = blockIdx.x & 31;
        int b   = blockIdx.x >> 5;
        int vbase = blk * (GV / BPB);

        float4* zp = pts_out + ((size_t)b * GV + vbase) / 4;
#pragma unroll
        for (int i = 0; i < 8; i++)
            zp[i * 256 + tid] = make_float4(0.f, 0.f, 0.f, 0.f);

        const float* bd = bnd + (size_t)b * GV + vbase;
        const float* nz = noise + (size_t)b * GV + vbase;

        U64 top[10];
#pragma unroll
        for (int k = 0; k < 10; k++) top[k] = 0ull;

        for (int i = 0; i < (GV / BPB) / 256; i++) {
            int e = i * 256 + tid;
            float bv = bd[e];
            float s  = nz[e];
            U64 p = (bv > 0.5f) ? 0ull
                  : ((((U64)__float_as_uint(s)) << 32) |
                     (IDXM - (unsigned)(vbase + e)));
            if (p > top[9]) {
#pragma unroll
                for (int k = 0; k < 10; k++) {
                    U64 mx = p > top[k] ? p : top[k];
                    U64 mn = p > top[k] ? top[k] : p;
                    top[k] = mx; p = mn;
                }
            }
        }

        U64* lcand = (U64*)pool;             // 2560 U64
        U64* rv    = (U64*)(pool + 20480);   // 256 U64
        int* rp    = (int*)(pool + 22528);   // 256 int
#pragma unroll
        for (int k = 0; k < 10; k++) lcand[tid * 10 + k] = top[k];
        __syncthreads();

        for (int pass = 0; pass < 10; pass++) {
            U64 bv = 0; int bp = 0;
            for (int i = tid; i < 2560; i += 256) {
                U64 xv = lcand[i];
                if (xv > bv) { bv = xv; bp = i; }
            }
            rv[tid] = bv; rp[tid] = bp;
            __syncthreads();
            for (int off = 128; off > 0; off >>= 1) {
                if (tid < off) {
                    if (rv[tid + off] > rv[tid]) { rv[tid] = rv[tid + off]; rp[tid] = rp[tid + off]; }
                }
                __syncthreads();
            }
            if (tid == 0) {
                cand[((size_t)b * BPB + blk) * 10 + pass] = rv[0];
                lcand[rp[0]] = 0ull;
            }
            __syncthreads();
        }
        return;
    }

    // ==================== convA (R12-proven body) ==========================
    int bid = blockIdx.x - 256;
    int box = bid & 255, b = bid >> 8;
    const float* bd = bnd + (size_t)b * GV;
    u16* zb = zbuf + (size_t)b * (NP * (size_t)GV);

    u16* halo  = (u16*)pool;              // 2378 u16 (+pad to 4768)
    u32* ybase = (u32*)(pool + 4768);     // 4 x 66*36 u32

    int z0 = (box >> 4) * 4, y0 = (box & 15) * 4;

    // coalesced weight stage (ybase region dead until GEMM phase)
    {
        float* ldsW = (float*)ybase;
        for (int i = tid; i < 3520; i += 256) {
            float v;
            if (i < 1728)      v = w1[i];
            else if (i < 3456) v = w2[i - 1728];
            else               v = b1[i - 3456];
            ldsW[i] = v;
        }
    }

    // halo fill (bf16 bit patterns 0x3F80 / 0)
    for (int i = tid; i < 2378; i += 256) {
        u16 hval = 0;
        if (i < 2376) {
            int hz = i / 396, rem = i - hz * 396;
            int hy = rem / 66, hx = rem - hy * 66;
            int gz = z0 + hz - 1, gy = y0 + hy - 1, gx = hx - 1;
            if (((unsigned)gz < (unsigned)G) & ((unsigned)gy < (unsigned)G) &
                ((unsigned)gx < (unsigned)G)) {
                float f = bd[(gz << 12) + (gy << 6) + gx];
                hval = (f > 0.5f) ? (u16)0x3F80 : (u16)0;
            }
        }
        halo[i] = hval;
    }

    __syncthreads();

    int wv = tid >> 6, lane = tid & 63;
    int g = lane >> 4, lr = lane & 15;

    const float* ldsW = (const float*)ybase;
    BF8 w1A[4];                     // GEMM1 A: 4 c-tiles, K=27 pad 32
#pragma unroll
    for (int m = 0; m < 4; m++) {
        int c = 16 * m + lr;
#pragma unroll
        for (int j = 0; j < 8; j++) {
            int kk = 8 * g + j;
            float w = (kk < 27) ? ldsW[c * 27 + kk] : 0.0f;
            w1A[m].s[j] = f2bf(w);
        }
    }
    BF8 w2dx[3][2];                 // GEMM2 A: rows p=(dz,dy)<9, t=3p+dx
#pragma unroll
    for (int dx = 0; dx < 3; dx++)
#pragma unroll
        for (int ks = 0; ks < 2; ks++)
#pragma unroll
            for (int j = 0; j < 8; j++) {
                int ch = 32 * ks + 8 * g + j;
                float w = (lr < NP) ? ldsW[1728 + ch * 27 + 3 * lr + dx] : 0.0f;
                w2dx[dx][ks].s[j] = f2bf(w);
            }
    float bias[4][4];               // b1 for D rows c = 16m+4g+r (exact f32)
#pragma unroll
    for (int m = 0; m < 4; m++)
#pragma unroll
        for (int r = 0; r < 4; r++) bias[m][r] = ldsW[3456 + 16 * m + 4 * g + r];

    int tapoff[8];
#pragma unroll
    for (int j = 0; j < 8; j++) {
        int kk = 8 * g + j;
        int kc = kk < 27 ? kk : 0;
        int dz = kc / 9, ry = kc - dz * 9;
        int dy = ry / 3, dxx = ry - dy * 3;
        tapoff[j] = dz * 396 + dy * 66 + dxx;
    }

    __syncthreads();    // weights region dead -> Y-line buffers

    u32* myY = ybase + wv * (66 * YSTRIDE);

    for (int li = 0; li < 4; li++) {
        int l = wv * 4 + li;
        int zl = l >> 2, yl = l & 3;
        int linebase = (zl * 6 + yl) * 66 + lr;
        int vbase = ((z0 + zl) << 12) + ((y0 + yl) << 6);

        // zero pad rows 0 (x=-1) and 65 (x=64)
        myY[(lane < 32 ? 0 : 65 * YSTRIDE) + (lane & 31)] = 0;

        // GEMM1 phase: fill Y-line rows 1..64
        for (int xt = 0; xt < 4; xt++) {
            int x0 = xt * 16;
            BF8 xB;
#pragma unroll
            for (int j = 0; j < 8; j++)
                xB.s[j] = halo[linebase + x0 + tapoff[j]];

            f32x4 yac[4];
#pragma unroll
            for (int m = 0; m < 4; m++) {
                f32x4 c0;
                c0[0] = bias[m][0]; c0[1] = bias[m][1];
                c0[2] = bias[m][2]; c0[3] = bias[m][3];
                yac[m] = __builtin_amdgcn_mfma_f32_16x16x32_bf16(
                    w1A[m].v, xB.v, c0, 0, 0, 0);
            }

            int rx = x0 + lr + 1;     // buffer row for x = x0+lr
#pragma unroll
            for (int m = 0; m < 4; m++) {
                float a0 = fmaxf(yac[m][0], 0.f), a1 = fmaxf(yac[m][1], 0.f);
                float a2 = fmaxf(yac[m][2], 0.f), a3 = fmaxf(yac[m][3], 0.f);
                u32 h01 = cvt_pk_bf16(a0, a1);
                u32 h23 = cvt_pk_bf16(a2, a3);
                *(U64*)&myY[rx * YSTRIDE + 8 * m + 2 * g] =
                    (U64)h01 | ((U64)h23 << 32);
            }
        }

        asm volatile("" ::: "memory");   // order line writes vs reads

        // GEMM2 phase: zrow = sum_dx W2dx @ Y(shifted)
        for (int xt = 0; xt < 4; xt++) {
            int x0 = xt * 16;
            f32x4 zac = f32x4{0.f, 0.f, 0.f, 0.f};
#pragma unroll
            for (int dx = 0; dx < 3; dx++) {
                int rbase = (x0 + lr + dx) * YSTRIDE;
#pragma unroll
                for (int ks = 0; ks < 2; ks++) {
                    bf16x8 yB = *(const bf16x8*)&myY[rbase + 16 * ks + 4 * g];
                    zac = __builtin_amdgcn_mfma_f32_16x16x32_bf16(
                        w2dx[dx][ks].v, yB, zac, 0, 0, 0);
                }
            }

            int vg = vbase + x0 + lr;
#pragma unroll
            for (int r = 0; r < 4; r++) {
                int p = 4 * g + r;
                if (p < NP)
                    zb[(size_t)p * GV + vg] = f2bf(zac[r]);
            }
        }

        asm volatile("" ::: "memory");   // line buffer reused next li
    }
}

// ---------------------------------------------------------------------------
// convB standalone (no LDS -> full occupancy): 9 coalesced zrow taps
// ---------------------------------------------------------------------------
__global__ __launch_bounds__(256) void convB_kernel(
    const u16* __restrict__ zbuf,
    float* __restrict__ xout,
    const float* __restrict__ b2)
{
    int b = blockIdx.y;
    const u16* zb = zbuf + (size_t)b * (NP * (size_t)GV);
    float* xo = xout + (size_t)b * GV;

    int v  = blockIdx.x * 256 + threadIdx.x;
    int zc = v >> 12, yc = (v >> 6) & 63, xc = v & 63;
    float acc = b2[0];
#pragma unroll
    for (int dz = 0; dz < 3; dz++)
#pragma unroll
    for (int dy = 0; dy < 3; dy++) {
        int p = dz * 3 + dy;
        int zz = zc + dz - 1, yy = yc + dy - 1;
        bool ok = ((unsigned)zz < (unsigned)G) & ((unsigned)yy < (unsigned)G);
        if (ok) acc += bf2f(zb[(size_t)p * GV + (zz << 12) + (yy << 6) + xc]);
    }
    xo[v] = fmaxf(acc, 0.0f);
}

// ---------------------------------------------------------------------------
// fc1 with XCD-aware remap (R13-proven)
// ---------------------------------------------------------------------------
__global__ __launch_bounds__(256) void fc1_kernel(
    const float* __restrict__ W, const float* __restrict__ x,
    float* __restrict__ pacc)
{
    int bid = blockIdx.x;           // 0..2047
    int xcd  = bid & 7;
    int slot = bid >> 3;            // 0..255
    int vc = (xcd << 3) | (slot >> 5);   // 0..63
    int jt = slot & 31;             // 0..31
    int tid = threadIdx.x;
    int j0 = jt * 8;
    size_t v0 = (size_t)vc * 4096;

    const f32x4* Wp[8];
#pragma unroll
    for (int jj = 0; jj < 8; jj++)
        Wp[jj] = reinterpret_cast<const f32x4*>(W + (size_t)(j0 + jj) * GV + v0);
    const f32x4* Xp[NB];
#pragma unroll
    for (int b = 0; b < NB; b++)
        Xp[b] = reinterpret_cast<const f32x4*>(x + (size_t)b * GV + v0);

    float acc[8][NB];
#pragma unroll
    for (int jj = 0; jj < 8; jj++)
#pragma unroll
        for (int b = 0; b < NB; b++) acc[jj][b] = 0.0f;

    for (int i = 0; i < 4; i++) {
        int e = i * 256 + tid;
        f32x4 wvv[8];
#pragma unroll
        for (int jj = 0; jj < 8; jj++)
            wvv[jj] = __builtin_nontemporal_load(&Wp[jj][e]);
        f32x4 xv[NB];
#pragma unroll
        for (int b = 0; b < NB; b++) xv[b] = Xp[b][e];
#pragma unroll
        for (int b = 0; b < NB; b++) {
#pragma unroll
            for (int jj = 0; jj < 8; jj++) {
                acc[jj][b] = fmaf(wvv[jj][0], xv[b][0], acc[jj][b]);
                acc[jj][b] = fmaf(wvv[jj][1], xv[b][1], acc[jj][b]);
                acc[jj][b] = fmaf(wvv[jj][2], xv[b][2], acc[jj][b]);
                acc[jj][b] = fmaf(wvv[jj][3], xv[b][3], acc[jj][b]);
            }
        }
    }

    __shared__ float sacc[256][36];
    __shared__ float p2[8][40];
#pragma unroll
    for (int pass = 0; pass < 2; pass++) {
        if (pass > 0) __syncthreads();
        float4* row = reinterpret_cast<float4*>(&sacc[tid][0]);
#pragma unroll
        for (int jj = 0; jj < 4; jj++) {
            int js = pass * 4 + jj;
            row[jj * 2 + 0] = make_float4(acc[js][0], acc[js][1], acc[js][2], acc[js][3]);
            row[jj * 2 + 1] = make_float4(acc[js][4], acc[js][5], acc[js][6], acc[js][7]);
        }
        __syncthreads();
        {
            int o = tid & 31, gg = tid >> 5;
            float s = 0.0f;
#pragma unroll
            for (int k = 0; k < 32; k++) s += sacc[gg * 32 + k][o];
            p2[gg][o] = s;
        }
        __syncthreads();
        if (tid < 32) {
            float s = 0.0f;
#pragma unroll
            for (int gg = 0; gg < 8; gg++) s += p2[gg][tid];
            int jj = tid >> 3, b = tid & 7;
            pacc[((size_t)b * 64 + vc) * 256 + (j0 + pass * 4 + jj)] = s;
        }
    }
}

// ---------------------------------------------------------------------------
// finalize: blocks 0..7 topk2 per batch; block 8 fc_final
// ---------------------------------------------------------------------------
__global__ __launch_bounds__(256) void finalize_kernel(
    const U64* __restrict__ cand, float* __restrict__ pts,
    const float* __restrict__ pacc, const float* __restrict__ fc1_b,
    const float* __restrict__ fc2_w, const float* __restrict__ fc2_b,
    float* __restrict__ prob)
{
    int tid = threadIdx.x;

    if (blockIdx.x < 8) {
        int b = blockIdx.x;
        __shared__ U64 lc[BPB * 10];
        __shared__ U64 rv[256];
        __shared__ int rp[256];
        __shared__ int widx[10];
        for (int i = tid; i < BPB * 10; i += 256) lc[i] = cand[(size_t)b * BPB * 10 + i];
        __syncthreads();

        for (int pass = 0; pass < 10; pass++) {
            U64 bv = 0; int bp = 0;
            for (int i = tid; i < BPB * 10; i += 256) {
                U64 xv = lc[i];
                if (xv > bv) { bv = xv; bp = i; }
            }
            rv[tid] = bv; rp[tid] = bp;
            __syncthreads();
            for (int off = 128; off > 0; off >>= 1) {
                if (tid < off) {
                    if (rv[tid + off] > rv[tid]) { rv[tid] = rv[tid + off]; rp[tid] = rp[tid + off]; }
                }
                __syncthreads();
            }
            if (tid == 0) { widx[pass] = (int)(IDXM - (u32)(rv[0] & 0xffffffffu)); lc[rp[0]] = 0ull; }
            __syncthreads();
        }
        if (tid < 10) pts[(size_t)b * GV + widx[tid]] = 1.0f;
    } else {
        int j = tid;
        float h[NB];
#pragma unroll
        for (int b = 0; b < NB; b++) h[b] = 0.0f;
        for (int c = 0; c < 64; c++) {
#pragma unroll
            for (int b = 0; b < NB; b++)
                h[b] += pacc[((size_t)b * 64 + c) * 256 + j];
        }
        float w2j = fc2_w[j];
        float contrib[NB];
#pragma unroll
        for (int b = 0; b < NB; b++)
            contrib[b] = fmaxf(h[b] + fc1_b[j], 0.0f) * w2j;

        int lane = j & 63, wid = j >> 6;
#pragma unroll
        for (int b = 0; b < NB; b++)
#pragma unroll
            for (int off = 32; off > 0; off >>= 1)
                contrib[b] += __shfl_down(contrib[b], off, 64);

        __shared__ float sred[4][NB];
        if (lane == 0) {
#pragma unroll
            for (int b = 0; b < NB; b++) sred[wid][b] = contrib[b];
        }
        __syncthreads();
        if (j < NB) {
            float t = sred[0][j] + sred[1][j] + sred[2][j] + sred[3][j] + fc2_b[0];
            prob[j] = 100.0f / (1.0f + expf(-t));
        }
    }
}

// ---------------------------------------------------------------------------
extern "C" void kernel_launch(void* const* d_in, const int* in_sizes, int n_in,
                              void* d_out, int out_size, void* d_ws, size_t ws_size,
                              hipStream_t stream)
{
    const float* bnd   = (const float*)d_in[0];
    const float* w1    = (const float*)d_in[1];
    const float* b1    = (const float*)d_in[2];
    const float* w2    = (const float*)d_in[3];
    const float* b2    = (const float*)d_in[4];
    const float* fw1   = (const float*)d_in[5];
    const float* fb1   = (const float*)d_in[6];
    const float* fw2   = (const float*)d_in[7];
    const float* fb2   = (const float*)d_in[8];
    const float* noise = (const float*)d_in[9];

    float* out = (float*)d_out;
    char* ws = (char*)d_ws;

    const size_t xbuf_off = 0;                                 // 8 MB
    const size_t pacc_off = xbuf_off + (size_t)NB * GV * 4;    // 512 KB
    const size_t cand_off = pacc_off + (size_t)NB * 64 * 256 * 4;
    const size_t zbuf_off = cand_off + (size_t)NB * BPB * 10 * 8;

    float* xbuf = (float*)(ws + xbuf_off);
    float* pacc = (float*)(ws + pacc_off);
    U64*   cand = (U64*)(ws + cand_off);
    u16*   zbuf = (u16*)(ws + zbuf_off);                       // 8 x 4.5 MB

    // dispatch 1: topk1 (blocks 0..255, overlaps) + convA (blocks 256..2303)
    convA_topk_kernel<<<2304, 256, 0, stream>>>(bnd, w1, b1, w2, zbuf,
                                                noise, cand, (float4*)out);

    dim3 gB(GV / 256, NB);
    convB_kernel<<<gB, 256, 0, stream>>>(zbuf, xbuf, b2);

    fc1_kernel<<<2048, 256, 0, stream>>>(fw1, xbuf, pacc);

    finalize_kernel<<<9, 256, 0, stream>>>(cand, out, pacc, fb1, fw2, fb2,
                                           out + (size_t)NB * GV);
}

// Round 15
// 150.320 us; speedup vs baseline: 1.7921x; 1.0972x over previous
//
#include <hip/hip_runtime.h>
#include <math.h>

#define G 64
#define GV (G*G*G)      // 262144
#define NB 8
#define NP 9            // zrow planes (dz,dy)

typedef unsigned char u8;
typedef unsigned short u16;
typedef unsigned int u32;
typedef unsigned long long U64;
typedef __bf16 bf16x8 __attribute__((ext_vector_type(8)));
typedef float f32x4 __attribute__((ext_vector_type(4)));

union BF8 { u16 s[8]; bf16x8 v; };

__device__ __forceinline__ float bf2f(u16 h) {
    union { u32 u; float f; } c; c.u = ((u32)h) << 16; return c.f;
}
__device__ __forceinline__ u16 f2bf(float f) {
    union { float f; u32 u; } c; c.f = f;
    u32 u = c.u;
    return (u16)((u + 0x7fffu + ((u >> 16) & 1u)) >> 16);   // RNE
}
__device__ __forceinline__ u32 cvt_pk_bf16(float lo, float hi) {
    u32 r;
    asm volatile("v_cvt_pk_bf16_f32 %0, %1, %2" : "=v"(r) : "v"(lo), "v"(hi));
    return r;
}

#define YSTRIDE 36   // u32 per x-row; stride%32=4 banks -> free 2-way conflict
#define BPB 32
#define IDXM 0x3FFFFu
#define POOLB 40448  // u8 halo (2384) + Ylds (38016) = 40400 -> 4 blocks/CU

// ---------------------------------------------------------------------------
// Merged dispatch 1: blocks 0..255 = topk1 (indep of convA; zeroes points,
// writes cand) — overlaps under convA's compute. blocks 256..2303 = convA.
// __launch_bounds__(256,4): cap VGPR so the 4-block/CU LDS occupancy lands.
// ---------------------------------------------------------------------------
__global__ __launch_bounds__(256, 4) void convA_topk_kernel(
    const float* __restrict__ bnd,
    const float* __restrict__ w1, const float* __restrict__ b1,
    const float* __restrict__ w2,
    u16* __restrict__ zbuf,
    const float* __restrict__ noise,
    U64* __restrict__ cand, float4* __restrict__ pts_out)
{
    __shared__ __align__(16) char pool[POOLB];
    int tid = threadIdx.x;

    if (blockIdx.x < 256) {
        // ================= topk1 (also zeros points output) ================
        int blk = blockIdx.x & 31;
        int b   = blockIdx.x >> 5;
        int vbase = blk * (GV / BPB);

        float4* zp = pts_out + ((size_t)b * GV + vbase) / 4;
#pragma unroll
        for (int i = 0; i < 8; i++)
            zp[i * 256 + tid] = make_float4(0.f, 0.f, 0.f, 0.f);

        const float* bd = bnd + (size_t)b * GV + vbase;
        const float* nz = noise + (size_t)b * GV + vbase;

        U64 top[10];
#pragma unroll
        for (int k = 0; k < 10; k++) top[k] = 0ull;

        for (int i = 0; i < (GV / BPB) / 256; i++) {
            int e = i * 256 + tid;
            float bv = bd[e];
            float s  = nz[e];
            U64 p = (bv > 0.5f) ? 0ull
                  : ((((U64)__float_as_uint(s)) << 32) |
                     (IDXM - (unsigned)(vbase + e)));
            if (p > top[9]) {
#pragma unroll
                for (int k = 0; k < 10; k++) {
                    U64 mx = p > top[k] ? p : top[k];
                    U64 mn = p > top[k] ? top[k] : p;
                    top[k] = mx; p = mn;
                }
            }
        }

        U64* lcand = (U64*)pool;             // 2560 U64
        U64* rv    = (U64*)(pool + 20480);   // 256 U64
        int* rp    = (int*)(pool + 22528);   // 256 int
#pragma unroll
        for (int k = 0; k < 10; k++) lcand[tid * 10 + k] = top[k];
        __syncthreads();

        for (int pass = 0; pass < 10; pass++) {
            U64 bv = 0; int bp = 0;
            for (int i = tid; i < 2560; i += 256) {
                U64 xv = lcand[i];
                if (xv > bv) { bv = xv; bp = i; }
            }
            rv[tid] = bv; rp[tid] = bp;
            __syncthreads();
            for (int off = 128; off > 0; off >>= 1) {
                if (tid < off) {
                    if (rv[tid + off] > rv[tid]) { rv[tid] = rv[tid + off]; rp[tid] = rp[tid + off]; }
                }
                __syncthreads();
            }
            if (tid == 0) {
                cand[((size_t)b * BPB + blk) * 10 + pass] = rv[0];
                lcand[rp[0]] = 0ull;
            }
            __syncthreads();
        }
        return;
    }

    // ==================== convA (R12 body, u8 halo) ========================
    int bid = blockIdx.x - 256;
    int box = bid & 255, b = bid >> 8;
    const float* bd = bnd + (size_t)b * GV;
    u16* zb = zbuf + (size_t)b * (NP * (size_t)GV);

    u8*  halo8 = (u8*)pool;               // 2378 u8 flags (+pad to 2384)
    u32* ybase = (u32*)(pool + 2384);     // 4 x 66*36 u32

    int z0 = (box >> 4) * 4, y0 = (box & 15) * 4;

    // coalesced weight stage (ybase region dead until GEMM phase)
    {
        float* ldsW = (float*)ybase;
        for (int i = tid; i < 3520; i += 256) {
            float v;
            if (i < 1728)      v = w1[i];
            else if (i < 3456) v = w2[i - 1728];
            else               v = b1[i - 3456];
            ldsW[i] = v;
        }
    }

    // halo fill (u8 occupancy flags)
    for (int i = tid; i < 2378; i += 256) {
        u8 hval = 0;
        if (i < 2376) {
            int hz = i / 396, rem = i - hz * 396;
            int hy = rem / 66, hx = rem - hy * 66;
            int gz = z0 + hz - 1, gy = y0 + hy - 1, gx = hx - 1;
            if (((unsigned)gz < (unsigned)G) & ((unsigned)gy < (unsigned)G) &
                ((unsigned)gx < (unsigned)G)) {
                float f = bd[(gz << 12) + (gy << 6) + gx];
                hval = (f > 0.5f) ? (u8)1 : (u8)0;
            }
        }
        halo8[i] = hval;
    }

    __syncthreads();

    int wv = tid >> 6, lane = tid & 63;
    int g = lane >> 4, lr = lane & 15;

    const float* ldsW = (const float*)ybase;
    BF8 w1A[4];                     // GEMM1 A: 4 c-tiles, K=27 pad 32
#pragma unroll
    for (int m = 0; m < 4; m++) {
        int c = 16 * m + lr;
#pragma unroll
        for (int j = 0; j < 8; j++) {
            int kk = 8 * g + j;
            float w = (kk < 27) ? ldsW[c * 27 + kk] : 0.0f;
            w1A[m].s[j] = f2bf(w);
        }
    }
    BF8 w2dx[3][2];                 // GEMM2 A: rows p=(dz,dy)<9, t=3p+dx
#pragma unroll
    for (int dx = 0; dx < 3; dx++)
#pragma unroll
        for (int ks = 0; ks < 2; ks++)
#pragma unroll
            for (int j = 0; j < 8; j++) {
                int ch = 32 * ks + 8 * g + j;
                float w = (lr < NP) ? ldsW[1728 + ch * 27 + 3 * lr + dx] : 0.0f;
                w2dx[dx][ks].s[j] = f2bf(w);
            }
    float bias[4][4];               // b1 for D rows c = 16m+4g+r (exact f32)
#pragma unroll
    for (int m = 0; m < 4; m++)
#pragma unroll
        for (int r = 0; r < 4; r++) bias[m][r] = ldsW[3456 + 16 * m + 4 * g + r];

    int tapoff[8];
#pragma unroll
    for (int j = 0; j < 8; j++) {
        int kk = 8 * g + j;
        int kc = kk < 27 ? kk : 0;
        int dz = kc / 9, ry = kc - dz * 9;
        int dy = ry / 3, dxx = ry - dy * 3;
        tapoff[j] = dz * 396 + dy * 66 + dxx;
    }

    __syncthreads();    // weights region dead -> Y-line buffers

    u32* myY = ybase + wv * (66 * YSTRIDE);

    for (int li = 0; li < 4; li++) {
        int l = wv * 4 + li;
        int zl = l >> 2, yl = l & 3;
        int linebase = (zl * 6 + yl) * 66 + lr;
        int vbase = ((z0 + zl) << 12) + ((y0 + yl) << 6);

        // zero pad rows 0 (x=-1) and 65 (x=64)
        myY[(lane < 32 ? 0 : 65 * YSTRIDE) + (lane & 31)] = 0;

        // GEMM1 phase: fill Y-line rows 1..64
        for (int xt = 0; xt < 4; xt++) {
            int x0 = xt * 16;
            BF8 xB;
#pragma unroll
            for (int j = 0; j < 8; j++) {
                u16 f = (u16)halo8[linebase + x0 + tapoff[j]];
                xB.s[j] = (u16)(f * 0x3F80u);
            }

            f32x4 yac[4];
#pragma unroll
            for (int m = 0; m < 4; m++) {
                f32x4 c0;
                c0[0] = bias[m][0]; c0[1] = bias[m][1];
                c0[2] = bias[m][2]; c0[3] = bias[m][3];
                yac[m] = __builtin_amdgcn_mfma_f32_16x16x32_bf16(
                    w1A[m].v, xB.v, c0, 0, 0, 0);
            }

            int rx = x0 + lr + 1;     // buffer row for x = x0+lr
#pragma unroll
            for (int m = 0; m < 4; m++) {
                float a0 = fmaxf(yac[m][0], 0.f), a1 = fmaxf(yac[m][1], 0.f);
                float a2 = fmaxf(yac[m][2], 0.f), a3 = fmaxf(yac[m][3], 0.f);
                u32 h01 = cvt_pk_bf16(a0, a1);
                u32 h23 = cvt_pk_bf16(a2, a3);
                *(U64*)&myY[rx * YSTRIDE + 8 * m + 2 * g] =
                    (U64)h01 | ((U64)h23 << 32);
            }
        }

        asm volatile("" ::: "memory");   // order line writes vs reads

        // GEMM2 phase: zrow = sum_dx W2dx @ Y(shifted)
        for (int xt = 0; xt < 4; xt++) {
            int x0 = xt * 16;
            f32x4 zac = f32x4{0.f, 0.f, 0.f, 0.f};
#pragma unroll
            for (int dx = 0; dx < 3; dx++) {
                int rbase = (x0 + lr + dx) * YSTRIDE;
#pragma unroll
                for (int ks = 0; ks < 2; ks++) {
                    bf16x8 yB = *(const bf16x8*)&myY[rbase + 16 * ks + 4 * g];
                    zac = __builtin_amdgcn_mfma_f32_16x16x32_bf16(
                        w2dx[dx][ks].v, yB, zac, 0, 0, 0);
                }
            }

            int vg = vbase + x0 + lr;
#pragma unroll
            for (int r = 0; r < 4; r++) {
                int p = 4 * g + r;
                if (p < NP) {
                    u32 pk = cvt_pk_bf16(zac[r], zac[r]);   // HW RNE
                    zb[(size_t)p * GV + vg] = (u16)pk;
                }
            }
        }

        asm volatile("" ::: "memory");   // line buffer reused next li
    }
}

// ---------------------------------------------------------------------------
// convB standalone (no LDS -> full occupancy): 9 coalesced zrow taps
// ---------------------------------------------------------------------------
__global__ __launch_bounds__(256) void convB_kernel(
    const u16* __restrict__ zbuf,
    float* __restrict__ xout,
    const float* __restrict__ b2)
{
    int b = blockIdx.y;
    const u16* zb = zbuf + (size_t)b * (NP * (size_t)GV);
    float* xo = xout + (size_t)b * GV;

    int v  = blockIdx.x * 256 + threadIdx.x;
    int zc = v >> 12, yc = (v >> 6) & 63, xc = v & 63;
    float acc = b2[0];
#pragma unroll
    for (int dz = 0; dz < 3; dz++)
#pragma unroll
    for (int dy = 0; dy < 3; dy++) {
        int p = dz * 3 + dy;
        int zz = zc + dz - 1, yy = yc + dy - 1;
        bool ok = ((unsigned)zz < (unsigned)G) & ((unsigned)yy < (unsigned)G);
        if (ok) acc += bf2f(zb[(size_t)p * GV + (zz << 12) + (yy << 6) + xc]);
    }
    xo[v] = fmaxf(acc, 0.0f);
}

// ---------------------------------------------------------------------------
// fc1 with XCD-aware remap (R13-proven)
// ---------------------------------------------------------------------------
__global__ __launch_bounds__(256) void fc1_kernel(
    const float* __restrict__ W, const float* __restrict__ x,
    float* __restrict__ pacc)
{
    int bid = blockIdx.x;           // 0..2047
    int xcd  = bid & 7;
    int slot = bid >> 3;            // 0..255
    int vc = (xcd << 3) | (slot >> 5);   // 0..63
    int jt = slot & 31;             // 0..31
    int tid = threadIdx.x;
    int j0 = jt * 8;
    size_t v0 = (size_t)vc * 4096;

    const f32x4* Wp[8];
#pragma unroll
    for (int jj = 0; jj < 8; jj++)
        Wp[jj] = reinterpret_cast<const f32x4*>(W + (size_t)(j0 + jj) * GV + v0);
    const f32x4* Xp[NB];
#pragma unroll
    for (int b = 0; b < NB; b++)
        Xp[b] = reinterpret_cast<const f32x4*>(x + (size_t)b * GV + v0);

    float acc[8][NB];
#pragma unroll
    for (int jj = 0; jj < 8; jj++)
#pragma unroll
        for (int b = 0; b < NB; b++) acc[jj][b] = 0.0f;

    for (int i = 0; i < 4; i++) {
        int e = i * 256 + tid;
        f32x4 wvv[8];
#pragma unroll
        for (int jj = 0; jj < 8; jj++)
            wvv[jj] = __builtin_nontemporal_load(&Wp[jj][e]);
        f32x4 xv[NB];
#pragma unroll
        for (int b = 0; b < NB; b++) xv[b] = Xp[b][e];
#pragma unroll
        for (int b = 0; b < NB; b++) {
#pragma unroll
            for (int jj = 0; jj < 8; jj++) {
                acc[jj][b] = fmaf(wvv[jj][0], xv[b][0], acc[jj][b]);
                acc[jj][b] = fmaf(wvv[jj][1], xv[b][1], acc[jj][b]);
                acc[jj][b] = fmaf(wvv[jj][2], xv[b][2], acc[jj][b]);
                acc[jj][b] = fmaf(wvv[jj][3], xv[b][3], acc[jj][b]);
            }
        }
    }

    __shared__ float sacc[256][36];
    __shared__ float p2[8][40];
#pragma unroll
    for (int pass = 0; pass < 2; pass++) {
        if (pass > 0) __syncthreads();
        float4* row = reinterpret_cast<float4*>(&sacc[tid][0]);
#pragma unroll
        for (int jj = 0; jj < 4; jj++) {
            int js = pass * 4 + jj;
            row[jj * 2 + 0] = make_float4(acc[js][0], acc[js][1], acc[js][2], acc[js][3]);
            row[jj * 2 + 1] = make_float4(acc[js][4], acc[js][5], acc[js][6], acc[js][7]);
        }
        __syncthreads();
        {
            int o = tid & 31, gg = tid >> 5;
            float s = 0.0f;
#pragma unroll
            for (int k = 0; k < 32; k++) s += sacc[gg * 32 + k][o];
            p2[gg][o] = s;
        }
        __syncthreads();
        if (tid < 32) {
            float s = 0.0f;
#pragma unroll
            for (int gg = 0; gg < 8; gg++) s += p2[gg][tid];
            int jj = tid >> 3, b = tid & 7;
            pacc[((size_t)b * 64 + vc) * 256 + (j0 + pass * 4 + jj)] = s;
        }
    }
}

// ---------------------------------------------------------------------------
// finalize: blocks 0..7 topk2 per batch; block 8 fc_final
// ---------------------------------------------------------------------------
__global__ __launch_bounds__(256) void finalize_kernel(
    const U64* __restrict__ cand, float* __restrict__ pts,
    const float* __restrict__ pacc, const float* __restrict__ fc1_b,
    const float* __restrict__ fc2_w, const float* __restrict__ fc2_b,
    float* __restrict__ prob)
{
    int tid = threadIdx.x;

    if (blockIdx.x < 8) {
        int b = blockIdx.x;
        __shared__ U64 lc[BPB * 10];
        __shared__ U64 rv[256];
        __shared__ int rp[256];
        __shared__ int widx[10];
        for (int i = tid; i < BPB * 10; i += 256) lc[i] = cand[(size_t)b * BPB * 10 + i];
        __syncthreads();

        for (int pass = 0; pass < 10; pass++) {
            U64 bv = 0; int bp = 0;
            for (int i = tid; i < BPB * 10; i += 256) {
                U64 xv = lc[i];
                if (xv > bv) { bv = xv; bp = i; }
            }
            rv[tid] = bv; rp[tid] = bp;
            __syncthreads();
            for (int off = 128; off > 0; off >>= 1) {
                if (tid < off) {
                    if (rv[tid + off] > rv[tid]) { rv[tid] = rv[tid + off]; rp[tid] = rp[tid + off]; }
                }
                __syncthreads();
            }
            if (tid == 0) { widx[pass] = (int)(IDXM - (u32)(rv[0] & 0xffffffffu)); lc[rp[0]] = 0ull; }
            __syncthreads();
        }
        if (tid < 10) pts[(size_t)b * GV + widx[tid]] = 1.0f;
    } else {
        int j = tid;
        float h[NB];
#pragma unroll
        for (int b = 0; b < NB; b++) h[b] = 0.0f;
        for (int c = 0; c < 64; c++) {
#pragma unroll
            for (int b = 0; b < NB; b++)
                h[b] += pacc[((size_t)b * 64 + c) * 256 + j];
        }
        float w2j = fc2_w[j];
        float contrib[NB];
#pragma unroll
        for (int b = 0; b < NB; b++)
            contrib[b] = fmaxf(h[b] + fc1_b[j], 0.0f) * w2j;

        int lane = j & 63, wid = j >> 6;
#pragma unroll
        for (int b = 0; b < NB; b++)
#pragma unroll
            for (int off = 32; off > 0; off >>= 1)
                contrib[b] += __shfl_down(contrib[b], off, 64);

        __shared__ float sred[4][NB];
        if (lane == 0) {
#pragma unroll
            for (int b = 0; b < NB; b++) sred[wid][b] = contrib[b];
        }
        __syncthreads();
        if (j < NB) {
            float t = sred[0][j] + sred[1][j] + sred[2][j] + sred[3][j] + fc2_b[0];
            prob[j] = 100.0f / (1.0f + expf(-t));
        }
    }
}

// ---------------------------------------------------------------------------
extern "C" void kernel_launch(void* const* d_in, const int* in_sizes, int n_in,
                              void* d_out, int out_size, void* d_ws, size_t ws_size,
                              hipStream_t stream)
{
    const float* bnd   = (const float*)d_in[0];
    const float* w1    = (const float*)d_in[1];
    const float* b1    = (const float*)d_in[2];
    const float* w2    = (const float*)d_in[3];
    const float* b2    = (const float*)d_in[4];
    const float* fw1   = (const float*)d_in[5];
    const float* fb1   = (const float*)d_in[6];
    const float* fw2   = (const float*)d_in[7];
    const float* fb2   = (const float*)d_in[8];
    const float* noise = (const float*)d_in[9];

    float* out = (float*)d_out;
    char* ws = (char*)d_ws;

    const size_t xbuf_off = 0;                                 // 8 MB
    const size_t pacc_off = xbuf_off + (size_t)NB * GV * 4;    // 512 KB
    const size_t cand_off = pacc_off + (size_t)NB * 64 * 256 * 4;
    const size_t zbuf_off = cand_off + (size_t)NB * BPB * 10 * 8;

    float* xbuf = (float*)(ws + xbuf_off);
    float* pacc = (float*)(ws + pacc_off);
    U64*   cand = (U64*)(ws + cand_off);
    u16*   zbuf = (u16*)(ws + zbuf_off);                       // 8 x 4.5 MB

    // dispatch 1: topk1 (blocks 0..255, overlaps) + convA (blocks 256..2303)
    convA_topk_kernel<<<2304, 256, 0, stream>>>(bnd, w1, b1, w2, zbuf,
                                                noise, cand, (float4*)out);

    dim3 gB(GV / 256, NB);
    convB_kernel<<<gB, 256, 0, stream>>>(zbuf, xbuf, b2);

    fc1_kernel<<<2048, 256, 0, stream>>>(fw1, xbuf, pacc);

    finalize_kernel<<<9, 256, 0, stream>>>(cand, out, pacc, fb1, fw2, fb2,
                                           out + (size_t)NB * GV);
}

// Round 16
// 145.640 us; speedup vs baseline: 1.8496x; 1.0321x over previous
//
#include <hip/hip_runtime.h>
#include <math.h>

#define G 64
#define GV (G*G*G)      // 262144
#define NB 8
#define NP 9            // zrow planes (dz,dy)

typedef unsigned char u8;
typedef unsigned short u16;
typedef unsigned int u32;
typedef unsigned long long U64;
typedef __bf16 bf16x8 __attribute__((ext_vector_type(8)));
typedef float f32x4 __attribute__((ext_vector_type(4)));

union BF8 { u16 s[8]; bf16x8 v; };

__device__ __forceinline__ float bf2f(u16 h) {
    union { u32 u; float f; } c; c.u = ((u32)h) << 16; return c.f;
}
__device__ __forceinline__ u16 f2bf(float f) {
    union { float f; u32 u; } c; c.f = f;
    u32 u = c.u;
    return (u16)((u + 0x7fffu + ((u >> 16) & 1u)) >> 16);   // RNE
}
__device__ __forceinline__ u32 cvt_pk_bf16(float lo, float hi) {
    u32 r;
    asm volatile("v_cvt_pk_bf16_f32 %0, %1, %2" : "=v"(r) : "v"(lo), "v"(hi));
    return r;
}

#define YSTRIDE 36   // u32 per x-row; stride%32=4 banks -> free 2-way conflict
#define BPB 32
#define IDXM 0x3FFFFu
#define POOLB 40448  // u8 halo (2384) + Ylds (38016) = 40400 -> 4 blocks/CU

// ---------------------------------------------------------------------------
// Merged dispatch 1: blocks 0..255 = topk1 (indep of convA; zeroes points,
// writes cand) — overlaps under convA's compute. blocks 256..2303 = convA.
// __launch_bounds__(256,4): cap VGPR so the 4-block/CU LDS occupancy lands.
// ---------------------------------------------------------------------------
__global__ __launch_bounds__(256, 4) void convA_topk_kernel(
    const float* __restrict__ bnd,
    const float* __restrict__ w1, const float* __restrict__ b1,
    const float* __restrict__ w2,
    u16* __restrict__ zbuf,
    const float* __restrict__ noise,
    U64* __restrict__ cand, float4* __restrict__ pts_out)
{
    __shared__ __align__(16) char pool[POOLB];
    int tid = threadIdx.x;

    if (blockIdx.x < 256) {
        // ================= topk1 (also zeros points output) ================
        int blk = blockIdx.x & 31;
        int b   = blockIdx.x >> 5;
        int vbase = blk * (GV / BPB);

        float4* zp = pts_out + ((size_t)b * GV + vbase) / 4;
#pragma unroll
        for (int i = 0; i < 8; i++)
            zp[i * 256 + tid] = make_float4(0.f, 0.f, 0.f, 0.f);

        const float* bd = bnd + (size_t)b * GV + vbase;
        const float* nz = noise + (size_t)b * GV + vbase;

        U64 top[10];
#pragma unroll
        for (int k = 0; k < 10; k++) top[k] = 0ull;

        for (int i = 0; i < (GV / BPB) / 256; i++) {
            int e = i * 256 + tid;
            float bv = bd[e];
            float s  = nz[e];
            U64 p = (bv > 0.5f) ? 0ull
                  : ((((U64)__float_as_uint(s)) << 32) |
                     (IDXM - (unsigned)(vbase + e)));
            if (p > top[9]) {
#pragma unroll
                for (int k = 0; k < 10; k++) {
                    U64 mx = p > top[k] ? p : top[k];
                    U64 mn = p > top[k] ? top[k] : p;
                    top[k] = mx; p = mn;
                }
            }
        }

        U64* lcand = (U64*)pool;             // 2560 U64
        U64* rv    = (U64*)(pool + 20480);   // 256 U64
        int* rp    = (int*)(pool + 22528);   // 256 int
#pragma unroll
        for (int k = 0; k < 10; k++) lcand[tid * 10 + k] = top[k];
        __syncthreads();

        for (int pass = 0; pass < 10; pass++) {
            U64 bv = 0; int bp = 0;
            for (int i = tid; i < 2560; i += 256) {
                U64 xv = lcand[i];
                if (xv > bv) { bv = xv; bp = i; }
            }
            rv[tid] = bv; rp[tid] = bp;
            __syncthreads();
            for (int off = 128; off > 0; off >>= 1) {
                if (tid < off) {
                    if (rv[tid + off] > rv[tid]) { rv[tid] = rv[tid + off]; rp[tid] = rp[tid + off]; }
                }
                __syncthreads();
            }
            if (tid == 0) {
                cand[((size_t)b * BPB + blk) * 10 + pass] = rv[0];
                lcand[rp[0]] = 0ull;
            }
            __syncthreads();
        }
        return;
    }

    // ==================== convA (R15 body, u8 halo) ========================
    int bid = blockIdx.x - 256;
    int box = bid & 255, b = bid >> 8;
    const float* bd = bnd + (size_t)b * GV;
    u16* zb = zbuf + (size_t)b * (NP * (size_t)GV);

    u8*  halo8 = (u8*)pool;               // 2378 u8 flags (+pad to 2384)
    u32* ybase = (u32*)(pool + 2384);     // 4 x 66*36 u32

    int z0 = (box >> 4) * 4, y0 = (box & 15) * 4;

    // coalesced weight stage (ybase region dead until GEMM phase)
    {
        float* ldsW = (float*)ybase;
        for (int i = tid; i < 3520; i += 256) {
            float v;
            if (i < 1728)      v = w1[i];
            else if (i < 3456) v = w2[i - 1728];
            else               v = b1[i - 3456];
            ldsW[i] = v;
        }
    }

    // halo fill (u8 occupancy flags)
    for (int i = tid; i < 2378; i += 256) {
        u8 hval = 0;
        if (i < 2376) {
            int hz = i / 396, rem = i - hz * 396;
            int hy = rem / 66, hx = rem - hy * 66;
            int gz = z0 + hz - 1, gy = y0 + hy - 1, gx = hx - 1;
            if (((unsigned)gz < (unsigned)G) & ((unsigned)gy < (unsigned)G) &
                ((unsigned)gx < (unsigned)G)) {
                float f = bd[(gz << 12) + (gy << 6) + gx];
                hval = (f > 0.5f) ? (u8)1 : (u8)0;
            }
        }
        halo8[i] = hval;
    }

    __syncthreads();

    int wv = tid >> 6, lane = tid & 63;
    int g = lane >> 4, lr = lane & 15;

    const float* ldsW = (const float*)ybase;
    BF8 w1A[4];                     // GEMM1 A: 4 c-tiles, K=27 pad 32
#pragma unroll
    for (int m = 0; m < 4; m++) {
        int c = 16 * m + lr;
#pragma unroll
        for (int j = 0; j < 8; j++) {
            int kk = 8 * g + j;
            float w = (kk < 27) ? ldsW[c * 27 + kk] : 0.0f;
            w1A[m].s[j] = f2bf(w);
        }
    }
    BF8 w2dx[3][2];                 // GEMM2 A: rows p=(dz,dy)<9, t=3p+dx
#pragma unroll
    for (int dx = 0; dx < 3; dx++)
#pragma unroll
        for (int ks = 0; ks < 2; ks++)
#pragma unroll
            for (int j = 0; j < 8; j++) {
                int ch = 32 * ks + 8 * g + j;
                float w = (lr < NP) ? ldsW[1728 + ch * 27 + 3 * lr + dx] : 0.0f;
                w2dx[dx][ks].s[j] = f2bf(w);
            }
    float bias[4][4];               // b1 for D rows c = 16m+4g+r (exact f32)
#pragma unroll
    for (int m = 0; m < 4; m++)
#pragma unroll
        for (int r = 0; r < 4; r++) bias[m][r] = ldsW[3456 + 16 * m + 4 * g + r];

    int tapoff[8];
#pragma unroll
    for (int j = 0; j < 8; j++) {
        int kk = 8 * g + j;
        int kc = kk < 27 ? kk : 0;
        int dz = kc / 9, ry = kc - dz * 9;
        int dy = ry / 3, dxx = ry - dy * 3;
        tapoff[j] = dz * 396 + dy * 66 + dxx;
    }

    __syncthreads();    // weights region dead -> Y-line buffers

    u32* myY = ybase + wv * (66 * YSTRIDE);

    for (int li = 0; li < 4; li++) {
        int l = wv * 4 + li;
        int zl = l >> 2, yl = l & 3;
        int linebase = (zl * 6 + yl) * 66 + lr;
        int vbase = ((z0 + zl) << 12) + ((y0 + yl) << 6);

        // zero pad rows 0 (x=-1) and 65 (x=64)
        myY[(lane < 32 ? 0 : 65 * YSTRIDE) + (lane & 31)] = 0;

        // GEMM1 phase: fill Y-line rows 1..64
        for (int xt = 0; xt < 4; xt++) {
            int x0 = xt * 16;
            BF8 xB;
#pragma unroll
            for (int j = 0; j < 8; j++) {
                u16 f = (u16)halo8[linebase + x0 + tapoff[j]];
                xB.s[j] = (u16)(f * 0x3F80u);
            }

            f32x4 yac[4];
#pragma unroll
            for (int m = 0; m < 4; m++) {
                f32x4 c0;
                c0[0] = bias[m][0]; c0[1] = bias[m][1];
                c0[2] = bias[m][2]; c0[3] = bias[m][3];
                yac[m] = __builtin_amdgcn_mfma_f32_16x16x32_bf16(
                    w1A[m].v, xB.v, c0, 0, 0, 0);
            }

            int rx = x0 + lr + 1;     // buffer row for x = x0+lr
#pragma unroll
            for (int m = 0; m < 4; m++) {
                float a0 = fmaxf(yac[m][0], 0.f), a1 = fmaxf(yac[m][1], 0.f);
                float a2 = fmaxf(yac[m][2], 0.f), a3 = fmaxf(yac[m][3], 0.f);
                u32 h01 = cvt_pk_bf16(a0, a1);
                u32 h23 = cvt_pk_bf16(a2, a3);
                *(U64*)&myY[rx * YSTRIDE + 8 * m + 2 * g] =
                    (U64)h01 | ((U64)h23 << 32);
            }
        }

        asm volatile("" ::: "memory");   // order line writes vs reads

        // GEMM2 phase: zrow = sum_dx W2dx @ Y(shifted)
        for (int xt = 0; xt < 4; xt++) {
            int x0 = xt * 16;
            f32x4 zac = f32x4{0.f, 0.f, 0.f, 0.f};
#pragma unroll
            for (int dx = 0; dx < 3; dx++) {
                int rbase = (x0 + lr + dx) * YSTRIDE;
#pragma unroll
                for (int ks = 0; ks < 2; ks++) {
                    bf16x8 yB = *(const bf16x8*)&myY[rbase + 16 * ks + 4 * g];
                    zac = __builtin_amdgcn_mfma_f32_16x16x32_bf16(
                        w2dx[dx][ks].v, yB, zac, 0, 0, 0);
                }
            }

            int vg = vbase + x0 + lr;
#pragma unroll
            for (int r = 0; r < 4; r++) {
                int p = 4 * g + r;
                if (p < NP) {
                    u32 pk = cvt_pk_bf16(zac[r], zac[r]);   // HW RNE
                    zb[(size_t)p * GV + vg] = (u16)pk;
                }
            }
        }

        asm volatile("" ::: "memory");   // line buffer reused next li
    }
}

// ---------------------------------------------------------------------------
// convB vectorized: 8 voxels/thread along x (taps shift only in z/y, so the
// x-segment stays 16B-aligned -> one uint4 load per tap).
// ---------------------------------------------------------------------------
__global__ __launch_bounds__(256) void convB_kernel(
    const u16* __restrict__ zbuf,
    float* __restrict__ xout,
    const float* __restrict__ b2)
{
    int b = blockIdx.y;
    const u16* zb = zbuf + (size_t)b * (NP * (size_t)GV);
    float* xo = xout + (size_t)b * GV;

    int t8 = blockIdx.x * 256 + threadIdx.x;    // 0..32767
    int v0 = t8 * 8;
    int zc = v0 >> 12, yc = (v0 >> 6) & 63, x0 = v0 & 63;

    float bb = b2[0];
    float acc[8];
#pragma unroll
    for (int i = 0; i < 8; i++) acc[i] = bb;

#pragma unroll
    for (int dz = 0; dz < 3; dz++)
#pragma unroll
    for (int dy = 0; dy < 3; dy++) {
        int p = dz * 3 + dy;
        int zz = zc + dz - 1, yy = yc + dy - 1;
        bool ok = ((unsigned)zz < (unsigned)G) & ((unsigned)yy < (unsigned)G);
        if (ok) {
            const uint4* src = (const uint4*)(zb + (size_t)p * GV +
                                              (zz << 12) + (yy << 6) + x0);
            uint4 d = *src;
            u32 w[4] = {d.x, d.y, d.z, d.w};
#pragma unroll
            for (int q = 0; q < 4; q++) {
                acc[2 * q]     += bf2f((u16)(w[q] & 0xffffu));
                acc[2 * q + 1] += bf2f((u16)(w[q] >> 16));
            }
        }
    }

    float4* o = (float4*)(xo + v0);
    o[0] = make_float4(fmaxf(acc[0], 0.f), fmaxf(acc[1], 0.f),
                       fmaxf(acc[2], 0.f), fmaxf(acc[3], 0.f));
    o[1] = make_float4(fmaxf(acc[4], 0.f), fmaxf(acc[5], 0.f),
                       fmaxf(acc[6], 0.f), fmaxf(acc[7], 0.f));
}

// ---------------------------------------------------------------------------
// fc1 with XCD-aware remap (R13-proven)
// ---------------------------------------------------------------------------
__global__ __launch_bounds__(256) void fc1_kernel(
    const float* __restrict__ W, const float* __restrict__ x,
    float* __restrict__ pacc)
{
    int bid = blockIdx.x;           // 0..2047
    int xcd  = bid & 7;
    int slot = bid >> 3;            // 0..255
    int vc = (xcd << 3) | (slot >> 5);   // 0..63
    int jt = slot & 31;             // 0..31
    int tid = threadIdx.x;
    int j0 = jt * 8;
    size_t v0 = (size_t)vc * 4096;

    const f32x4* Wp[8];
#pragma unroll
    for (int jj = 0; jj < 8; jj++)
        Wp[jj] = reinterpret_cast<const f32x4*>(W + (size_t)(j0 + jj) * GV + v0);
    const f32x4* Xp[NB];
#pragma unroll
    for (int b = 0; b < NB; b++)
        Xp[b] = reinterpret_cast<const f32x4*>(x + (size_t)b * GV + v0);

    float acc[8][NB];
#pragma unroll
    for (int jj = 0; jj < 8; jj++)
#pragma unroll
        for (int b = 0; b < NB; b++) acc[jj][b] = 0.0f;

    for (int i = 0; i < 4; i++) {
        int e = i * 256 + tid;
        f32x4 wvv[8];
#pragma unroll
        for (int jj = 0; jj < 8; jj++)
            wvv[jj] = __builtin_nontemporal_load(&Wp[jj][e]);
        f32x4 xv[NB];
#pragma unroll
        for (int b = 0; b < NB; b++) xv[b] = Xp[b][e];
#pragma unroll
        for (int b = 0; b < NB; b++) {
#pragma unroll
            for (int jj = 0; jj < 8; jj++) {
                acc[jj][b] = fmaf(wvv[jj][0], xv[b][0], acc[jj][b]);
                acc[jj][b] = fmaf(wvv[jj][1], xv[b][1], acc[jj][b]);
                acc[jj][b] = fmaf(wvv[jj][2], xv[b][2], acc[jj][b]);
                acc[jj][b] = fmaf(wvv[jj][3], xv[b][3], acc[jj][b]);
            }
        }
    }

    __shared__ float sacc[256][36];
    __shared__ float p2[8][40];
#pragma unroll
    for (int pass = 0; pass < 2; pass++) {
        if (pass > 0) __syncthreads();
        float4* row = reinterpret_cast<float4*>(&sacc[tid][0]);
#pragma unroll
        for (int jj = 0; jj < 4; jj++) {
            int js = pass * 4 + jj;
            row[jj * 2 + 0] = make_float4(acc[js][0], acc[js][1], acc[js][2], acc[js][3]);
            row[jj * 2 + 1] = make_float4(acc[js][4], acc[js][5], acc[js][6], acc[js][7]);
        }
        __syncthreads();
        {
            int o = tid & 31, gg = tid >> 5;
            float s = 0.0f;
#pragma unroll
            for (int k = 0; k < 32; k++) s += sacc[gg * 32 + k][o];
            p2[gg][o] = s;
        }
        __syncthreads();
        if (tid < 32) {
            float s = 0.0f;
#pragma unroll
            for (int gg = 0; gg < 8; gg++) s += p2[gg][tid];
            int jj = tid >> 3, b = tid & 7;
            pacc[((size_t)b * 64 + vc) * 256 + (j0 + pass * 4 + jj)] = s;
        }
    }
}

// ---------------------------------------------------------------------------
// finalize: blocks 0..7 topk2 per batch; block 8 fc_final
// ---------------------------------------------------------------------------
__global__ __launch_bounds__(256) void finalize_kernel(
    const U64* __restrict__ cand, float* __restrict__ pts,
    const float* __restrict__ pacc, const float* __restrict__ fc1_b,
    const float* __restrict__ fc2_w, const float* __restrict__ fc2_b,
    float* __restrict__ prob)
{
    int tid = threadIdx.x;

    if (blockIdx.x < 8) {
        int b = blockIdx.x;
        __shared__ U64 lc[BPB * 10];
        __shared__ U64 rv[256];
        __shared__ int rp[256];
        __shared__ int widx[10];
        for (int i = tid; i < BPB * 10; i += 256) lc[i] = cand[(size_t)b * BPB * 10 + i];
        __syncthreads();

        for (int pass = 0; pass < 10; pass++) {
            U64 bv = 0; int bp = 0;
            for (int i = tid; i < BPB * 10; i += 256) {
                U64 xv = lc[i];
                if (xv > bv) { bv = xv; bp = i; }
            }
            rv[tid] = bv; rp[tid] = bp;
            __syncthreads();
            for (int off = 128; off > 0; off >>= 1) {
                if (tid < off) {
                    if (rv[tid + off] > rv[tid]) { rv[tid] = rv[tid + off]; rp[tid] = rp[tid + off]; }
                }
                __syncthreads();
            }
            if (tid == 0) { widx[pass] = (int)(IDXM - (u32)(rv[0] & 0xffffffffu)); lc[rp[0]] = 0ull; }
            __syncthreads();
        }
        if (tid < 10) pts[(size_t)b * GV + widx[tid]] = 1.0f;
    } else {
        int j = tid;
        float h[NB];
#pragma unroll
        for (int b = 0; b < NB; b++) h[b] = 0.0f;
        for (int c = 0; c < 64; c++) {
#pragma unroll
            for (int b = 0; b < NB; b++)
                h[b] += pacc[((size_t)b * 64 + c) * 256 + j];
        }
        float w2j = fc2_w[j];
        float contrib[NB];
#pragma unroll
        for (int b = 0; b < NB; b++)
            contrib[b] = fmaxf(h[b] + fc1_b[j], 0.0f) * w2j;

        int lane = j & 63, wid = j >> 6;
#pragma unroll
        for (int b = 0; b < NB; b++)
#pragma unroll
            for (int off = 32; off > 0; off >>= 1)
                contrib[b] += __shfl_down(contrib[b], off, 64);

        __shared__ float sred[4][NB];
        if (lane == 0) {
#pragma unroll
            for (int b = 0; b < NB; b++) sred[wid][b] = contrib[b];
        }
        __syncthreads();
        if (j < NB) {
            float t = sred[0][j] + sred[1][j] + sred[2][j] + sred[3][j] + fc2_b[0];
            prob[j] = 100.0f / (1.0f + expf(-t));
        }
    }
}

// ---------------------------------------------------------------------------
extern "C" void kernel_launch(void* const* d_in, const int* in_sizes, int n_in,
                              void* d_out, int out_size, void* d_ws, size_t ws_size,
                              hipStream_t stream)
{
    const float* bnd   = (const float*)d_in[0];
    const float* w1    = (const float*)d_in[1];
    const float* b1    = (const float*)d_in[2];
    const float* w2    = (const float*)d_in[3];
    const float* b2    = (const float*)d_in[4];
    const float* fw1   = (const float*)d_in[5];
    const float* fb1   = (const float*)d_in[6];
    const float* fw2   = (const float*)d_in[7];
    const float* fb2   = (const float*)d_in[8];
    const float* noise = (const float*)d_in[9];

    float* out = (float*)d_out;
    char* ws = (char*)d_ws;

    const size_t xbuf_off = 0;                                 // 8 MB
    const size_t pacc_off = xbuf_off + (size_t)NB * GV * 4;    // 512 KB
    const size_t cand_off = pacc_off + (size_t)NB * 64 * 256 * 4;
    const size_t zbuf_off = cand_off + (size_t)NB * BPB * 10 * 8;

    float* xbuf = (float*)(ws + xbuf_off);
    float* pacc = (float*)(ws + pacc_off);
    U64*   cand = (U64*)(ws + cand_off);
    u16*   zbuf = (u16*)(ws + zbuf_off);                       // 8 x 4.5 MB

    // dispatch 1: topk1 (blocks 0..255, overlaps) + convA (blocks 256..2303)
    convA_topk_kernel<<<2304, 256, 0, stream>>>(bnd, w1, b1, w2, zbuf,
                                                noise, cand, (float4*)out);

    dim3 gB(GV / (8 * 256), NB);    // (128, 8) — 8 voxels/thread
    convB_kernel<<<gB, 256, 0, stream>>>(zbuf, xbuf, b2);

    fc1_kernel<<<2048, 256, 0, stream>>>(fw1, xbuf, pacc);

    finalize_kernel<<<9, 256, 0, stream>>>(cand, out, pacc, fb1, fw2, fb2,
                                           out + (size_t)NB * GV);
}

// Round 17
// 139.924 us; speedup vs baseline: 1.9252x; 1.0409x over previous
//
#include <hip/hip_runtime.h>
#include <math.h>

#define G 64
#define GV (G*G*G)      // 262144
#define NB 8
#define NP 9            // zrow planes (dz,dy)

typedef unsigned char u8;
typedef unsigned short u16;
typedef unsigned int u32;
typedef unsigned long long U64;
typedef __bf16 bf16x8 __attribute__((ext_vector_type(8)));
typedef float f32x4 __attribute__((ext_vector_type(4)));
typedef unsigned short u16x4 __attribute__((ext_vector_type(4)));

union BF8 { u16 s[8]; bf16x8 v; };

__device__ __forceinline__ float bf2f(u16 h) {
    union { u32 u; float f; } c; c.u = ((u32)h) << 16; return c.f;
}
__device__ __forceinline__ u16 f2bf(float f) {
    union { float f; u32 u; } c; c.f = f;
    u32 u = c.u;
    return (u16)((u + 0x7fffu + ((u >> 16) & 1u)) >> 16);   // RNE
}
__device__ __forceinline__ u32 cvt_pk_bf16(float lo, float hi) {
    u32 r;
    asm volatile("v_cvt_pk_bf16_f32 %0, %1, %2" : "=v"(r) : "v"(lo), "v"(hi));
    return r;
}

#define YSTRIDE 36   // u32 per x-row; stride%32=4 banks -> free 2-way conflict
#define BPB 32
#define IDXM 0x3FFFFu
#define POOLB 40448  // u8 halo (2384) + Ylds (38016) = 40400 -> 4 blocks/CU

// ---------------------------------------------------------------------------
// Dispatch 1: blocks 0..255 = topk1 (zeroes points, writes cand);
//             blocks 256..2303 = convA (R15-proven body).
// ---------------------------------------------------------------------------
__global__ __launch_bounds__(256, 4) void convA_topk_kernel(
    const float* __restrict__ bnd,
    const float* __restrict__ w1, const float* __restrict__ b1,
    const float* __restrict__ w2,
    u16* __restrict__ zbuf,
    const float* __restrict__ noise,
    U64* __restrict__ cand, float4* __restrict__ pts_out)
{
    __shared__ __align__(16) char pool[POOLB];
    int tid = threadIdx.x;

    if (blockIdx.x < 256) {
        // ================= topk1 (also zeros points output) ================
        int blk = blockIdx.x & 31;
        int b   = blockIdx.x >> 5;
        int vbase = blk * (GV / BPB);

        float4* zp = pts_out + ((size_t)b * GV + vbase) / 4;
#pragma unroll
        for (int i = 0; i < 8; i++)
            zp[i * 256 + tid] = make_float4(0.f, 0.f, 0.f, 0.f);

        const float* bd = bnd + (size_t)b * GV + vbase;
        const float* nz = noise + (size_t)b * GV + vbase;

        U64 top[10];
#pragma unroll
        for (int k = 0; k < 10; k++) top[k] = 0ull;

        for (int i = 0; i < (GV / BPB) / 256; i++) {
            int e = i * 256 + tid;
            float bv = bd[e];
            float s  = nz[e];
            U64 p = (bv > 0.5f) ? 0ull
                  : ((((U64)__float_as_uint(s)) << 32) |
                     (IDXM - (unsigned)(vbase + e)));
            if (p > top[9]) {
#pragma unroll
                for (int k = 0; k < 10; k++) {
                    U64 mx = p > top[k] ? p : top[k];
                    U64 mn = p > top[k] ? top[k] : p;
                    top[k] = mx; p = mn;
                }
            }
        }

        U64* lcand = (U64*)pool;             // 2560 U64
        U64* rv    = (U64*)(pool + 20480);   // 256 U64
        int* rp    = (int*)(pool + 22528);   // 256 int
#pragma unroll
        for (int k = 0; k < 10; k++) lcand[tid * 10 + k] = top[k];
        __syncthreads();

        for (int pass = 0; pass < 10; pass++) {
            U64 bv = 0; int bp = 0;
            for (int i = tid; i < 2560; i += 256) {
                U64 xv = lcand[i];
                if (xv > bv) { bv = xv; bp = i; }
            }
            rv[tid] = bv; rp[tid] = bp;
            __syncthreads();
            for (int off = 128; off > 0; off >>= 1) {
                if (tid < off) {
                    if (rv[tid + off] > rv[tid]) { rv[tid] = rv[tid + off]; rp[tid] = rp[tid + off]; }
                }
                __syncthreads();
            }
            if (tid == 0) {
                cand[((size_t)b * BPB + blk) * 10 + pass] = rv[0];
                lcand[rp[0]] = 0ull;
            }
            __syncthreads();
        }
        return;
    }

    // ==================== convA (u8 halo) ==================================
    int bid = blockIdx.x - 256;
    int box = bid & 255, b = bid >> 8;
    const float* bd = bnd + (size_t)b * GV;
    u16* zb = zbuf + (size_t)b * (NP * (size_t)GV);

    u8*  halo8 = (u8*)pool;               // 2378 u8 flags (+pad to 2384)
    u32* ybase = (u32*)(pool + 2384);     // 4 x 66*36 u32

    int z0 = (box >> 4) * 4, y0 = (box & 15) * 4;

    // coalesced weight stage (ybase region dead until GEMM phase)
    {
        float* ldsW = (float*)ybase;
        for (int i = tid; i < 3520; i += 256) {
            float v;
            if (i < 1728)      v = w1[i];
            else if (i < 3456) v = w2[i - 1728];
            else               v = b1[i - 3456];
            ldsW[i] = v;
        }
    }

    // halo fill (u8 occupancy flags)
    for (int i = tid; i < 2378; i += 256) {
        u8 hval = 0;
        if (i < 2376) {
            int hz = i / 396, rem = i - hz * 396;
            int hy = rem / 66, hx = rem - hy * 66;
            int gz = z0 + hz - 1, gy = y0 + hy - 1, gx = hx - 1;
            if (((unsigned)gz < (unsigned)G) & ((unsigned)gy < (unsigned)G) &
                ((unsigned)gx < (unsigned)G)) {
                float f = bd[(gz << 12) + (gy << 6) + gx];
                hval = (f > 0.5f) ? (u8)1 : (u8)0;
            }
        }
        halo8[i] = hval;
    }

    __syncthreads();

    int wv = tid >> 6, lane = tid & 63;
    int g = lane >> 4, lr = lane & 15;

    const float* ldsW = (const float*)ybase;
    BF8 w1A[4];                     // GEMM1 A: 4 c-tiles, K=27 pad 32
#pragma unroll
    for (int m = 0; m < 4; m++) {
        int c = 16 * m + lr;
#pragma unroll
        for (int j = 0; j < 8; j++) {
            int kk = 8 * g + j;
            float w = (kk < 27) ? ldsW[c * 27 + kk] : 0.0f;
            w1A[m].s[j] = f2bf(w);
        }
    }
    BF8 w2dx[3][2];                 // GEMM2 A: rows p=(dz,dy)<9, t=3p+dx
#pragma unroll
    for (int dx = 0; dx < 3; dx++)
#pragma unroll
        for (int ks = 0; ks < 2; ks++)
#pragma unroll
            for (int j = 0; j < 8; j++) {
                int ch = 32 * ks + 8 * g + j;
                float w = (lr < NP) ? ldsW[1728 + ch * 27 + 3 * lr + dx] : 0.0f;
                w2dx[dx][ks].s[j] = f2bf(w);
            }
    float bias[4][4];               // b1 for D rows c = 16m+4g+r (exact f32)
#pragma unroll
    for (int m = 0; m < 4; m++)
#pragma unroll
        for (int r = 0; r < 4; r++) bias[m][r] = ldsW[3456 + 16 * m + 4 * g + r];

    int tapoff[8];
#pragma unroll
    for (int j = 0; j < 8; j++) {
        int kk = 8 * g + j;
        int kc = kk < 27 ? kk : 0;
        int dz = kc / 9, ry = kc - dz * 9;
        int dy = ry / 3, dxx = ry - dy * 3;
        tapoff[j] = dz * 396 + dy * 66 + dxx;
    }

    __syncthreads();    // weights region dead -> Y-line buffers

    u32* myY = ybase + wv * (66 * YSTRIDE);

    for (int li = 0; li < 4; li++) {
        int l = wv * 4 + li;
        int zl = l >> 2, yl = l & 3;
        int linebase = (zl * 6 + yl) * 66 + lr;
        int vbase = ((z0 + zl) << 12) + ((y0 + yl) << 6);

        // zero pad rows 0 (x=-1) and 65 (x=64)
        myY[(lane < 32 ? 0 : 65 * YSTRIDE) + (lane & 31)] = 0;

        // GEMM1 phase: fill Y-line rows 1..64
        for (int xt = 0; xt < 4; xt++) {
            int x0 = xt * 16;
            BF8 xB;
#pragma unroll
            for (int j = 0; j < 8; j++) {
                u16 f = (u16)halo8[linebase + x0 + tapoff[j]];
                xB.s[j] = (u16)(f * 0x3F80u);
            }

            f32x4 yac[4];
#pragma unroll
            for (int m = 0; m < 4; m++) {
                f32x4 c0;
                c0[0] = bias[m][0]; c0[1] = bias[m][1];
                c0[2] = bias[m][2]; c0[3] = bias[m][3];
                yac[m] = __builtin_amdgcn_mfma_f32_16x16x32_bf16(
                    w1A[m].v, xB.v, c0, 0, 0, 0);
            }

            int rx = x0 + lr + 1;     // buffer row for x = x0+lr
#pragma unroll
            for (int m = 0; m < 4; m++) {
                float a0 = fmaxf(yac[m][0], 0.f), a1 = fmaxf(yac[m][1], 0.f);
                float a2 = fmaxf(yac[m][2], 0.f), a3 = fmaxf(yac[m][3], 0.f);
                u32 h01 = cvt_pk_bf16(a0, a1);
                u32 h23 = cvt_pk_bf16(a2, a3);
                *(U64*)&myY[rx * YSTRIDE + 8 * m + 2 * g] =
                    (U64)h01 | ((U64)h23 << 32);
            }
        }

        asm volatile("" ::: "memory");   // order line writes vs reads

        // GEMM2 phase: zrow = sum_dx W2dx @ Y(shifted)
        for (int xt = 0; xt < 4; xt++) {
            int x0 = xt * 16;
            f32x4 zac = f32x4{0.f, 0.f, 0.f, 0.f};
#pragma unroll
            for (int dx = 0; dx < 3; dx++) {
                int rbase = (x0 + lr + dx) * YSTRIDE;
#pragma unroll
                for (int ks = 0; ks < 2; ks++) {
                    bf16x8 yB = *(const bf16x8*)&myY[rbase + 16 * ks + 4 * g];
                    zac = __builtin_amdgcn_mfma_f32_16x16x32_bf16(
                        w2dx[dx][ks].v, yB, zac, 0, 0, 0);
                }
            }

            int vg = vbase + x0 + lr;
#pragma unroll
            for (int r = 0; r < 4; r++) {
                int p = 4 * g + r;
                if (p < NP) {
                    u32 pk = cvt_pk_bf16(zac[r], zac[r]);   // HW RNE
                    zb[(size_t)p * GV + vg] = (u16)pk;
                }
            }
        }

        asm volatile("" ::: "memory");   // line buffer reused next li
    }
}

// ---------------------------------------------------------------------------
// Dispatch 2: blocks 0..7 = topk2 (depends only on cand from dispatch 1);
//             blocks 8..1031 = convB, 8 voxels/thread, bf16 xbuf output.
// ---------------------------------------------------------------------------
__global__ __launch_bounds__(256) void convB_topk2_kernel(
    const u16* __restrict__ zbuf,
    u16* __restrict__ xout,
    const float* __restrict__ b2,
    const U64* __restrict__ cand, float* __restrict__ pts)
{
    int tid = threadIdx.x;

    if (blockIdx.x < 8) {
        // ================= topk2 =================
        int b = blockIdx.x;
        __shared__ U64 lc[BPB * 10];
        __shared__ U64 rv[256];
        __shared__ int rp[256];
        __shared__ int widx[10];
        for (int i = tid; i < BPB * 10; i += 256) lc[i] = cand[(size_t)b * BPB * 10 + i];
        __syncthreads();

        for (int pass = 0; pass < 10; pass++) {
            U64 bv = 0; int bp = 0;
            for (int i = tid; i < BPB * 10; i += 256) {
                U64 xv = lc[i];
                if (xv > bv) { bv = xv; bp = i; }
            }
            rv[tid] = bv; rp[tid] = bp;
            __syncthreads();
            for (int off = 128; off > 0; off >>= 1) {
                if (tid < off) {
                    if (rv[tid + off] > rv[tid]) { rv[tid] = rv[tid + off]; rp[tid] = rp[tid + off]; }
                }
                __syncthreads();
            }
            if (tid == 0) { widx[pass] = (int)(IDXM - (u32)(rv[0] & 0xffffffffu)); lc[rp[0]] = 0ull; }
            __syncthreads();
        }
        if (tid < 10) pts[(size_t)b * GV + widx[tid]] = 1.0f;
        return;
    }

    // ================= convB =================
    int r = blockIdx.x - 8;
    int vblk = r & 127, b = r >> 7;
    const u16* zb = zbuf + (size_t)b * (NP * (size_t)GV);
    u16* xo = xout + (size_t)b * GV;

    int t8 = vblk * 256 + tid;      // 0..32767
    int v0 = t8 * 8;
    int zc = v0 >> 12, yc = (v0 >> 6) & 63, x0 = v0 & 63;

    float bb = b2[0];
    float acc[8];
#pragma unroll
    for (int i = 0; i < 8; i++) acc[i] = bb;

#pragma unroll
    for (int dz = 0; dz < 3; dz++)
#pragma unroll
    for (int dy = 0; dy < 3; dy++) {
        int p = dz * 3 + dy;
        int zz = zc + dz - 1, yy = yc + dy - 1;
        bool ok = ((unsigned)zz < (unsigned)G) & ((unsigned)yy < (unsigned)G);
        if (ok) {
            const uint4* src = (const uint4*)(zb + (size_t)p * GV +
                                              (zz << 12) + (yy << 6) + x0);
            uint4 d = *src;
            u32 w[4] = {d.x, d.y, d.z, d.w};
#pragma unroll
            for (int q = 0; q < 4; q++) {
                acc[2 * q]     += bf2f((u16)(w[q] & 0xffffu));
                acc[2 * q + 1] += bf2f((u16)(w[q] >> 16));
            }
        }
    }

    uint4 o;
    o.x = cvt_pk_bf16(fmaxf(acc[0], 0.f), fmaxf(acc[1], 0.f));
    o.y = cvt_pk_bf16(fmaxf(acc[2], 0.f), fmaxf(acc[3], 0.f));
    o.z = cvt_pk_bf16(fmaxf(acc[4], 0.f), fmaxf(acc[5], 0.f));
    o.w = cvt_pk_bf16(fmaxf(acc[6], 0.f), fmaxf(acc[7], 0.f));
    *(uint4*)(xo + v0) = o;
}

// ---------------------------------------------------------------------------
// fc1 with XCD-aware remap; x is bf16 now (converted on load).
// ---------------------------------------------------------------------------
__global__ __launch_bounds__(256) void fc1_kernel(
    const float* __restrict__ W, const u16* __restrict__ x,
    float* __restrict__ pacc)
{
    int bid = blockIdx.x;           // 0..2047
    int xcd  = bid & 7;
    int slot = bid >> 3;            // 0..255
    int vc = (xcd << 3) | (slot >> 5);   // 0..63
    int jt = slot & 31;             // 0..31
    int tid = threadIdx.x;
    int j0 = jt * 8;
    size_t v0 = (size_t)vc * 4096;

    const f32x4* Wp[8];
#pragma unroll
    for (int jj = 0; jj < 8; jj++)
        Wp[jj] = reinterpret_cast<const f32x4*>(W + (size_t)(j0 + jj) * GV + v0);
    const u16* Xp[NB];
#pragma unroll
    for (int b = 0; b < NB; b++)
        Xp[b] = x + (size_t)b * GV + v0;

    float acc[8][NB];
#pragma unroll
    for (int jj = 0; jj < 8; jj++)
#pragma unroll
        for (int b = 0; b < NB; b++) acc[jj][b] = 0.0f;

    for (int i = 0; i < 4; i++) {
        int e = i * 256 + tid;
        f32x4 wvv[8];
#pragma unroll
        for (int jj = 0; jj < 8; jj++)
            wvv[jj] = __builtin_nontemporal_load(&Wp[jj][e]);
        f32x4 xv[NB];
#pragma unroll
        for (int b = 0; b < NB; b++) {
            u16x4 xr = *(const u16x4*)(Xp[b] + e * 4);
            xv[b][0] = bf2f(xr[0]); xv[b][1] = bf2f(xr[1]);
            xv[b][2] = bf2f(xr[2]); xv[b][3] = bf2f(xr[3]);
        }
#pragma unroll
        for (int b = 0; b < NB; b++) {
#pragma unroll
            for (int jj = 0; jj < 8; jj++) {
                acc[jj][b] = fmaf(wvv[jj][0], xv[b][0], acc[jj][b]);
                acc[jj][b] = fmaf(wvv[jj][1], xv[b][1], acc[jj][b]);
                acc[jj][b] = fmaf(wvv[jj][2], xv[b][2], acc[jj][b]);
                acc[jj][b] = fmaf(wvv[jj][3], xv[b][3], acc[jj][b]);
            }
        }
    }

    __shared__ float sacc[256][36];
    __shared__ float p2[8][40];
#pragma unroll
    for (int pass = 0; pass < 2; pass++) {
        if (pass > 0) __syncthreads();
        float4* row = reinterpret_cast<float4*>(&sacc[tid][0]);
#pragma unroll
        for (int jj = 0; jj < 4; jj++) {
            int js = pass * 4 + jj;
            row[jj * 2 + 0] = make_float4(acc[js][0], acc[js][1], acc[js][2], acc[js][3]);
            row[jj * 2 + 1] = make_float4(acc[js][4], acc[js][5], acc[js][6], acc[js][7]);
        }
        __syncthreads();
        {
            int o = tid & 31, gg = tid >> 5;
            float s = 0.0f;
#pragma unroll
            for (int k = 0; k < 32; k++) s += sacc[gg * 32 + k][o];
            p2[gg][o] = s;
        }
        __syncthreads();
        if (tid < 32) {
            float s = 0.0f;
#pragma unroll
            for (int gg = 0; gg < 8; gg++) s += p2[gg][tid];
            int jj = tid >> 3, b = tid & 7;
            pacc[((size_t)b * 64 + vc) * 256 + (j0 + pass * 4 + jj)] = s;
        }
    }
}

// ---------------------------------------------------------------------------
// fc_final: single block — sum chunks, bias, relu, fc2, sigmoid
// ---------------------------------------------------------------------------
__global__ __launch_bounds__(256) void fc_final_kernel(
    const float* __restrict__ pacc, const float* __restrict__ fc1_b,
    const float* __restrict__ fc2_w, const float* __restrict__ fc2_b,
    float* __restrict__ prob)
{
    int j = threadIdx.x;
    float h[NB];
#pragma unroll
    for (int b = 0; b < NB; b++) h[b] = 0.0f;
    for (int c = 0; c < 64; c++) {
#pragma unroll
        for (int b = 0; b < NB; b++)
            h[b] += pacc[((size_t)b * 64 + c) * 256 + j];
    }
    float w2j = fc2_w[j];
    float contrib[NB];
#pragma unroll
    for (int b = 0; b < NB; b++)
        contrib[b] = fmaxf(h[b] + fc1_b[j], 0.0f) * w2j;

    int lane = j & 63, wid = j >> 6;
#pragma unroll
    for (int b = 0; b < NB; b++)
#pragma unroll
        for (int off = 32; off > 0; off >>= 1)
            contrib[b] += __shfl_down(contrib[b], off, 64);

    __shared__ float sred[4][NB];
    if (lane == 0) {
#pragma unroll
        for (int b = 0; b < NB; b++) sred[wid][b] = contrib[b];
    }
    __syncthreads();
    if (j < NB) {
        float t = sred[0][j] + sred[1][j] + sred[2][j] + sred[3][j] + fc2_b[0];
        prob[j] = 100.0f / (1.0f + expf(-t));
    }
}

// ---------------------------------------------------------------------------
extern "C" void kernel_launch(void* const* d_in, const int* in_sizes, int n_in,
                              void* d_out, int out_size, void* d_ws, size_t ws_size,
                              hipStream_t stream)
{
    const float* bnd   = (const float*)d_in[0];
    const float* w1    = (const float*)d_in[1];
    const float* b1    = (const float*)d_in[2];
    const float* w2    = (const float*)d_in[3];
    const float* b2    = (const float*)d_in[4];
    const float* fw1   = (const float*)d_in[5];
    const float* fb1   = (const float*)d_in[6];
    const float* fw2   = (const float*)d_in[7];
    const float* fb2   = (const float*)d_in[8];
    const float* noise = (const float*)d_in[9];

    float* out = (float*)d_out;
    char* ws = (char*)d_ws;

    const size_t xbuf_off = 0;                                 // 4 MB (bf16)
    const size_t pacc_off = xbuf_off + (size_t)NB * GV * 2;    // 512 KB
    const size_t cand_off = pacc_off + (size_t)NB * 64 * 256 * 4;
    const size_t zbuf_off = cand_off + (size_t)NB * BPB * 10 * 8;

    u16*   xbuf = (u16*)(ws + xbuf_off);
    float* pacc = (float*)(ws + pacc_off);
    U64*   cand = (U64*)(ws + cand_off);
    u16*   zbuf = (u16*)(ws + zbuf_off);                       // 8 x 4.5 MB

    // dispatch 1: topk1 (blocks 0..255) + convA (blocks 256..2303)
    convA_topk_kernel<<<2304, 256, 0, stream>>>(bnd, w1, b1, w2, zbuf,
                                                noise, cand, (float4*)out);

    // dispatch 2: topk2 (blocks 0..7) + convB (blocks 8..1031)
    convB_topk2_kernel<<<1032, 256, 0, stream>>>(zbuf, xbuf, b2, cand, out);

    fc1_kernel<<<2048, 256, 0, stream>>>(fw1, xbuf, pacc);

    fc_final_kernel<<<1, 256, 0, stream>>>(pacc, fb1, fw2, fb2,
                                           out + (size_t)NB * GV);
}